// Round 15
// baseline (194.717 us; speedup 1.0000x reference)
//
#include <hip/hip_runtime.h>
#include <hip/hip_bf16.h>
#include <hip/hip_fp16.h>
#include <math.h>

#define T_TOK 3072
#define HID   1024
#define NH    16
#define HD    64
#define KVSPLIT 4
#define KVCHUNK (T_TOK / KVSPLIT)   // 768
#define NQB (T_TOK / 128)           // 24 q-tiles of 128 rows
#define LOG2E 1.4426950408889634f

typedef __attribute__((ext_vector_type(8))) short bf16x8;
typedef __attribute__((ext_vector_type(8))) unsigned short u16x8;
typedef __attribute__((ext_vector_type(4))) float f32x4;
typedef __attribute__((ext_vector_type(16))) float f32x16;
typedef __attribute__((ext_vector_type(4))) unsigned int u32x4;

#define VMCNT(n) asm volatile("s_waitcnt vmcnt(" #n ")" ::: "memory")
#define SB() __builtin_amdgcn_sched_barrier(0)

static __device__ __forceinline__ unsigned short f2bf(float x) {
  __hip_bfloat16 h = __float2bfloat16(x);
  return __builtin_bit_cast(unsigned short, h);
}
static __device__ __forceinline__ float bf2f(unsigned short u) {
  unsigned int v = (unsigned int)u << 16;
  return __builtin_bit_cast(float, v);
}
static __device__ __forceinline__ unsigned short f2h(float x) {
  __half h = __float2half(x);
  return __builtin_bit_cast(unsigned short, h);
}
static __device__ __forceinline__ float h2f(unsigned short u) {
  __half h = __builtin_bit_cast(__half, u);
  return __half2float(h);
}

// swizzled LDS short-index for a [rows][64 bf16] tile, row stride 128B (flash).
static __device__ __forceinline__ int swz(int row, int cb) {
  return row * 64 + ((cb ^ ((row & 7) << 4)) >> 1);
}

// ---------------- merged preprocessing (block-range dispatch) ----------------
__global__ __launch_bounds__(256) void prep(const float* __restrict__ X,
                                            const float* __restrict__ Wqkv,
                                            const float* __restrict__ Wo,
                                            const int* __restrict__ pos,
                                            const float* __restrict__ mask,
                                            unsigned short* __restrict__ Xb,
                                            unsigned short* __restrict__ WqkvT,
                                            unsigned short* __restrict__ WoT,
                                            float* __restrict__ ctab,
                                            float* __restrict__ stab,
                                            int* __restrict__ flags) {
  __shared__ float tile[32][33];
  __shared__ int sflag;
  const int b = blockIdx.x;
  const int tid = threadIdx.x;
  if (b < 3072) {
    int i = (b * 256 + tid) * 4;
    float4 v = *(const float4*)(X + i);
    ushort4 o;
    o.x = f2bf(v.x); o.y = f2bf(v.y); o.z = f2bf(v.z); o.w = f2bf(v.w);
    *(ushort4*)(Xb + i) = o;
  } else if (b < 6144) {
    int b2 = b - 3072;
    int c0 = (b2 % 96) * 32, r0 = (b2 / 96) * 32;
    int tx = tid & 31, ty = tid >> 5;
    #pragma unroll
    for (int i2 = 0; i2 < 32; i2 += 8)
      tile[ty + i2][tx] = Wqkv[(size_t)(r0 + ty + i2) * 3072 + c0 + tx];
    __syncthreads();
    #pragma unroll
    for (int i2 = 0; i2 < 32; i2 += 8)
      WqkvT[(size_t)(c0 + ty + i2) * 1024 + r0 + tx] = f2bf(tile[tx][ty + i2]);
  } else if (b < 7168) {
    int b2 = b - 6144;
    int c0 = (b2 % 32) * 32, r0 = (b2 / 32) * 32;
    int tx = tid & 31, ty = tid >> 5;
    #pragma unroll
    for (int i2 = 0; i2 < 32; i2 += 8)
      tile[ty + i2][tx] = Wo[(size_t)(r0 + ty + i2) * 1024 + c0 + tx];
    __syncthreads();
    #pragma unroll
    for (int i2 = 0; i2 < 32; i2 += 8)
      WoT[(size_t)(c0 + ty + i2) * 1024 + r0 + tx] = f2bf(tile[tx][ty + i2]);
  } else if (b < 7552) {
    int i = (b - 7168) * 256 + tid;   // T*32
    int t = i >> 5, j = i & 31;
    float inv = expf(-(float)j * 0.28782313662425572f);  // 10000^(-j/32)
    float f = (float)pos[t] * inv;
    ctab[i] = cosf(f);
    stab[i] = sinf(f);
  } else {
    int c = b - 7552;                 // 96 chunks
    int qx = c % NQB, z = c / NQB;
    const float* base = mask + (size_t)(qx * 128) * T_TOK + z * KVCHUNK;
    int any = 0;
    const int NC4 = KVCHUNK / 4;      // 192
    for (int i = tid; i < 128 * NC4; i += 256) {
      int row = i / NC4, cc = i - row * NC4;
      float4 v = *(const float4*)(base + (size_t)row * T_TOK + cc * 4);
      any |= (v.x != 0.f) | (v.y != 0.f) | (v.z != 0.f) | (v.w != 0.f);
    }
    if (tid == 0) sflag = 0;
    __syncthreads();
    if (__any(any) && (tid & 63) == 0) sflag = 1;  // benign same-value race
    __syncthreads();
    if (tid == 0) flags[z * NQB + qx] = sflag;
  }
}

// ---------------- fused RoPE split + V transpose (reads bf16 QKV once) ----------------
// V^T stored PERMUTED (swap bits 2<->3 of token-within-16) -> flash PV is
// shuffle-free with a single b128 LDS read per fragment.
__global__ __launch_bounds__(256) void rope_v(const unsigned short* __restrict__ QKVb,
                                              const float* __restrict__ ctab,
                                              const float* __restrict__ stab,
                                              unsigned short* __restrict__ Qh,
                                              unsigned short* __restrict__ Kh,
                                              unsigned short* __restrict__ Vt) {
  const float QSCL = 0.18033688011112042f;  // 0.125 * log2e
  const int h = blockIdx.y;
  const int t0 = blockIdx.x * 64;
  const int g = threadIdx.x & 3, tl = threadIdx.x >> 2;
  const int t = t0 + tl;
  __shared__ unsigned short vlds[64][72];

  const size_t rowb = (size_t)t * (3 * HID) + h * HD + g * 8;
  u16x8 qa = *(const u16x8*)(QKVb + rowb);
  u16x8 qb = *(const u16x8*)(QKVb + rowb + 32);
  u16x8 ka = *(const u16x8*)(QKVb + rowb + HID);
  u16x8 kb = *(const u16x8*)(QKVb + rowb + HID + 32);
  u16x8 va = *(const u16x8*)(QKVb + rowb + 2 * HID);
  u16x8 vb = *(const u16x8*)(QKVb + rowb + 2 * HID + 32);

  u16x8 qo0, qo1, ko0, ko1;
  #pragma unroll
  for (int e = 0; e < 8; ++e) {
    int j = g * 8 + e;
    float c = ctab[t * 32 + j], s = stab[t * 32 + j];
    float q1 = bf2f(qa[e]), q2 = bf2f(qb[e]);
    float k1 = bf2f(ka[e]), k2 = bf2f(kb[e]);
    qo0[e] = f2bf((q1 * c - q2 * s) * QSCL);
    qo1[e] = f2bf((q2 * c + q1 * s) * QSCL);
    ko0[e] = f2bf(k1 * c - k2 * s);
    ko1[e] = f2bf(k2 * c + k1 * s);
    vlds[tl][j] = va[e];
    vlds[tl][32 + j] = vb[e];
  }
  size_t ob = ((size_t)h * T_TOK + t) * HD + g * 8;
  *(u16x8*)(Qh + ob) = qo0;
  *(u16x8*)(Qh + ob + 32) = qo1;
  *(u16x8*)(Kh + ob) = ko0;
  *(u16x8*)(Kh + ob + 32) = ko1;

  __syncthreads();
  u16x8 o0, o1;
  #pragma unroll
  for (int e = 0; e < 8; ++e) {
    o0[e] = vlds[g * 16 + e][tl];
    o1[e] = vlds[g * 16 + 8 + e][tl];
  }
  u16x8 w0, w1;
  #pragma unroll
  for (int e = 0; e < 4; ++e) {
    w0[e] = o0[e];     w0[4 + e] = o1[e];
    w1[e] = o0[4 + e]; w1[4 + e] = o1[4 + e];
  }
  size_t vb2 = ((size_t)h * HD + tl) * T_TOK + t0 + g * 16;
  *(u16x8*)(Vt + vb2) = w0;
  *(u16x8*)(Vt + vb2 + 8) = w1;
}

// ---------------- GEMM: counted-vmcnt double-buffered pipeline (R12-proven) ----------------
template <int OBF16>
__device__ __forceinline__ void gemm_body(const unsigned short* __restrict__ A,
                                          const unsigned short* __restrict__ Bt,
                                          float* __restrict__ C,
                                          unsigned short* __restrict__ Cb,
                                          int M, int N, int K) {
  __shared__ unsigned short As[2][128 * 32];
  __shared__ unsigned short Bs[2][128 * 32];
  const int lane = threadIdx.x & 63;
  const int wv = threadIdx.x >> 6;
  const int wm = wv >> 1, wn = wv & 1;
  const int r = lane & 15, hi = lane >> 4;
  const int nwg = gridDim.x;                       // divisible by 8
  const int flat = blockIdx.x;
  const int sid = (flat & 7) * (nwg >> 3) + (flat >> 3);
  const int mblocks = M >> 7;
  const int m0 = (sid % mblocks) * 128, n0 = (sid / mblocks) * 128;

  const int srow = lane >> 2;                          // 0..15
  const int scb  = ((lane & 3) * 16) ^ ((srow & 3) << 4);
  const unsigned short* ga = A  + (size_t)(m0 + wv * 16 + srow) * K + (scb >> 1);
  const unsigned short* gb = Bt + (size_t)(n0 + wv * 16 + srow) * K + (scb >> 1);
  char* asd = (char*)&As[0][0] + wv * 1024;
  char* bsd = (char*)&Bs[0][0] + wv * 1024;

  auto stage = [&](int buf, int kt) {
    __builtin_amdgcn_global_load_lds(
        (const __attribute__((address_space(1))) unsigned int*)(ga + kt),
        (__attribute__((address_space(3))) unsigned int*)(asd + buf * 8192), 16, 0, 0);
    __builtin_amdgcn_global_load_lds(
        (const __attribute__((address_space(1))) unsigned int*)(ga + (size_t)64 * K + kt),
        (__attribute__((address_space(3))) unsigned int*)(asd + buf * 8192 + 4096), 16, 0, 0);
    __builtin_amdgcn_global_load_lds(
        (const __attribute__((address_space(1))) unsigned int*)(gb + kt),
        (__attribute__((address_space(3))) unsigned int*)(bsd + buf * 8192), 16, 0, 0);
    __builtin_amdgcn_global_load_lds(
        (const __attribute__((address_space(1))) unsigned int*)(gb + (size_t)64 * K + kt),
        (__attribute__((address_space(3))) unsigned int*)(bsd + buf * 8192 + 4096), 16, 0, 0);
  };

  f32x4 acc[4][4] = {};
  const int NT = K >> 5;
  stage(0, 0);
  #pragma unroll 2
  for (int it = 0; it < NT; ++it) {
    const int buf = it & 1;
    if (it + 1 < NT) {
      stage(buf ^ 1, (it + 1) * 32);
      VMCNT(4);
    } else {
      VMCNT(0);
    }
    SB();
    __builtin_amdgcn_s_barrier();
    SB();
    bf16x8 a[4], b[4];
    const int cbs = (hi * 16) ^ ((r & 3) << 4);
    #pragma unroll
    for (int tm = 0; tm < 4; ++tm)
      a[tm] = *(const bf16x8*)&As[buf][(wm * 64 + tm * 16 + r) * 32 + (cbs >> 1)];
    #pragma unroll
    for (int tn = 0; tn < 4; ++tn)
      b[tn] = *(const bf16x8*)&Bs[buf][(wn * 64 + tn * 16 + r) * 32 + (cbs >> 1)];
    #pragma unroll
    for (int tm = 0; tm < 4; ++tm)
      #pragma unroll
      for (int tn = 0; tn < 4; ++tn)
        acc[tm][tn] = __builtin_amdgcn_mfma_f32_16x16x32_bf16(a[tm], b[tn], acc[tm][tn], 0, 0, 0);
    __builtin_amdgcn_s_barrier();
  }
  #pragma unroll
  for (int tm = 0; tm < 4; ++tm)
    #pragma unroll
    for (int tn = 0; tn < 4; ++tn) {
      int colg = n0 + wn * 64 + tn * 16 + r;
      int rowg = m0 + wm * 64 + tm * 16 + hi * 4;
      if (OBF16) {
        unsigned short* cp = Cb + (size_t)rowg * N + colg;
        #pragma unroll
        for (int j = 0; j < 4; ++j) cp[(size_t)j * N] = f2bf(acc[tm][tn][j]);
      } else {
        float* cp = C + (size_t)rowg * N + colg;
        #pragma unroll
        for (int j = 0; j < 4; ++j) cp[(size_t)j * N] = acc[tm][tn][j];
      }
    }
}

__global__ __launch_bounds__(256) void gemm_bt(const unsigned short* __restrict__ A,
                                               const unsigned short* __restrict__ Bt,
                                               float* __restrict__ C, int M, int N, int K) {
  gemm_body<0>(A, Bt, C, nullptr, M, N, K);
}
__global__ __launch_bounds__(256) void gemm_bt_bf16(const unsigned short* __restrict__ A,
                                                    const unsigned short* __restrict__ Bt,
                                                    unsigned short* __restrict__ Cb,
                                                    int M, int N, int K) {
  gemm_body<1>(A, Bt, nullptr, Cb, M, N, K);
}

// ---------------- flash attention, NO-MASK kernel ----------------
// 24KB LDS (K dbuf 16KB + V single 8KB) + VGPR<=85 (launch_bounds 256,6):
// 6 blocks/CU = 24 waves/CU (vs 20). V staged at tile top; its L2-hit latency
// hides under QK^T; 3 barriers/tile (K-visible, V-visible, V-buf protect).
// Fixed softmax base m=0 (scores bounded for zero-mask path).
__global__ __launch_bounds__(256, 6) void flash_nomask(const unsigned short* __restrict__ Qh,
                                                       const unsigned short* __restrict__ Kh,
                                                       const unsigned short* __restrict__ Vt,
                                                       const int* __restrict__ flags,
                                                       unsigned short* __restrict__ Op,
                                                       float* __restrict__ Mp,
                                                       float* __restrict__ Lp) {
  const int NBLK = NH * NQB * KVSPLIT;              // 1536
  int id = blockIdx.x;
  int sid = (id & 7) * (NBLK / 8) + (id >> 3);      // XCD gets contiguous sid chunk
  const int hh = sid / (NQB * KVSPLIT);             // h slowest: 2 heads per XCD
  int rem = sid % (NQB * KVSPLIT);
  const int z  = rem / NQB;
  const int qx = rem % NQB;
  if (flags[z * NQB + qx]) return;                  // mask kernel handles this block
  const int q0 = qx * 128;
  const int kv0 = z * KVCHUNK;
  const int NT = KVCHUNK / 64;                      // 12

  __shared__ unsigned short Ks[2][64 * 64];         // 16KB
  __shared__ unsigned short Vs[64 * 64];            // 8KB
  const int lane = threadIdx.x & 63, wv = threadIdx.x >> 6;
  const int q31 = lane & 31, h2 = lane >> 5;
  const int qw = q0 + wv * 32 + q31;

  bf16x8 qf[4];
  #pragma unroll
  for (int ks = 0; ks < 4; ++ks)
    qf[ks] = *(const bf16x8*)(Qh + ((size_t)hh * T_TOK + qw) * HD + ks * 16 + h2 * 8);

  f32x16 acc_o[2] = {};
  float l = 0.f;

  const int ldrow = lane >> 3;
  const int colS  = ((lane & 7) * 16) ^ (ldrow << 4);
  const unsigned short* kga = Kh + ((size_t)hh * T_TOK + wv * 16 + ldrow) * HD + (colS >> 1);
  const unsigned short* vga = Vt + ((size_t)hh * HD + wv * 16 + ldrow) * T_TOK + (colS >> 1);
  char* ksd = (char*)&Ks[0][0] + wv * 2048;
  char* vsd = (char*)&Vs[0] + wv * 2048;

  auto stageK = [&](int buf, int s0) {
    __builtin_amdgcn_global_load_lds(
        (const __attribute__((address_space(1))) unsigned int*)(kga + (size_t)s0 * HD),
        (__attribute__((address_space(3))) unsigned int*)(ksd + buf * 8192), 16, 0, 0);
    __builtin_amdgcn_global_load_lds(
        (const __attribute__((address_space(1))) unsigned int*)(kga + (size_t)s0 * HD + 8 * HD),
        (__attribute__((address_space(3))) unsigned int*)(ksd + buf * 8192 + 1024), 16, 0, 0);
  };
  auto stageV = [&](int s0) {
    __builtin_amdgcn_global_load_lds(
        (const __attribute__((address_space(1))) unsigned int*)(vga + s0),
        (__attribute__((address_space(3))) unsigned int*)vsd, 16, 0, 0);
    __builtin_amdgcn_global_load_lds(
        (const __attribute__((address_space(1))) unsigned int*)(vga + s0 + 8 * T_TOK),
        (__attribute__((address_space(3))) unsigned int*)(vsd + 1024), 16, 0, 0);
  };

  stageK(0, kv0);  // prologue: K(0) in flight (2 loads)

  for (int it = 0; it < NT; ++it) {
    const int s0 = kv0 + it * 64;
    const int cur = it & 1;
    stageV(s0);                       // out: K(it)=2 + V(it)=2
    if (it + 1 < NT) {
      stageK(cur ^ 1, s0 + 64);       // out: 6
      VMCNT(4);                       // K(it) landed (own)
    } else {
      VMCNT(2);                       // K(it) landed (own)
    }
    SB();
    __builtin_amdgcn_s_barrier();     // all waves' K(it) visible
    SB();

    f32x16 as0 = {}, as1 = {};
    __builtin_amdgcn_s_setprio(1);
    #pragma unroll
    for (int ks = 0; ks < 4; ++ks) {
      bf16x8 kf0 = *(const bf16x8*)&Ks[cur][swz(q31,      ks * 32 + h2 * 16)];
      bf16x8 kf1 = *(const bf16x8*)&Ks[cur][swz(32 + q31, ks * 32 + h2 * 16)];
      as0 = __builtin_amdgcn_mfma_f32_32x32x16_bf16(kf0, qf[ks], as0, 0, 0, 0);
      as1 = __builtin_amdgcn_mfma_f32_32x32x16_bf16(kf1, qf[ks], as1, 0, 0, 0);
    }
    __builtin_amdgcn_s_setprio(0);

    // P = exp2(S) directly (fixed base 0); pack to bf16 pairs
    float ps = 0.f;
    unsigned int pk[16];
    #pragma unroll
    for (int kvb = 0; kvb < 2; ++kvb) {
      const f32x16& as = kvb ? as1 : as0;
      #pragma unroll
      for (int j = 0; j < 4; ++j) {
        float e0 = __builtin_amdgcn_exp2f(as[j * 4 + 0]);
        float e1 = __builtin_amdgcn_exp2f(as[j * 4 + 1]);
        float e2 = __builtin_amdgcn_exp2f(as[j * 4 + 2]);
        float e3 = __builtin_amdgcn_exp2f(as[j * 4 + 3]);
        ps += (e0 + e1) + (e2 + e3);
        pk[kvb * 8 + j * 2 + 0] = (unsigned int)f2bf(e0) | ((unsigned int)f2bf(e1) << 16);
        pk[kvb * 8 + j * 2 + 1] = (unsigned int)f2bf(e2) | ((unsigned int)f2bf(e3) << 16);
      }
    }
    l += ps;

    if (it + 1 < NT) VMCNT(2); else VMCNT(0);   // own V(it) landed (K(it+1) may fly)
    SB();
    __builtin_amdgcn_s_barrier();     // all waves' V(it) visible
    SB();

    __builtin_amdgcn_s_setprio(1);
    #pragma unroll
    for (int kvb = 0; kvb < 2; ++kvb)
      #pragma unroll
      for (int s = 0; s < 2; ++s) {
        u32x4 fr;
        fr[0] = pk[kvb * 8 + 4 * s + 0];
        fr[1] = pk[kvb * 8 + 4 * s + 1];
        fr[2] = pk[kvb * 8 + 4 * s + 2];
        fr[3] = pk[kvb * 8 + 4 * s + 3];
        bf16x8 pfrag = __builtin_bit_cast(bf16x8, fr);
        #pragma unroll
        for (int db = 0; db < 2; ++db) {
          bf16x8 vf = *(const bf16x8*)&Vs[swz(db * 32 + q31, kvb * 64 + s * 32 + h2 * 16)];
          acc_o[db] = __builtin_amdgcn_mfma_f32_32x32x16_bf16(vf, pfrag, acc_o[db], 0, 0, 0);
        }
      }
    __builtin_amdgcn_s_setprio(0);

    __builtin_amdgcn_s_barrier();     // protect Vs before next tile's stageV
  }

  float lf = l + __shfl_xor(l, 32);
  float lfinv = 1.f / lf;
  unsigned short* oprow = Op + (((size_t)z * T_TOK + qw) * NH + hh) * HD;
  #pragma unroll
  for (int db = 0; db < 2; ++db)
    #pragma unroll
    for (int g = 0; g < 4; ++g) {
      ushort4 o4;
      o4.x = f2h(acc_o[db][g * 4 + 0] * lfinv);
      o4.y = f2h(acc_o[db][g * 4 + 1] * lfinv);
      o4.z = f2h(acc_o[db][g * 4 + 2] * lfinv);
      o4.w = f2h(acc_o[db][g * 4 + 3] * lfinv);
      *(ushort4*)(oprow + db * 32 + g * 8 + 4 * h2) = o4;
    }
  if (h2 == 0) {
    size_t mi = ((size_t)z * T_TOK + qw) * NH + hh;
    Mp[mi] = 0.f;
    Lp[mi] = lf;
  }
}

// ---------------- flash attention, MASK kernel (R13 path; early-exit if no mask) ----------------
__global__ __launch_bounds__(256) void flash_mask(const unsigned short* __restrict__ Qh,
                                                  const unsigned short* __restrict__ Kh,
                                                  const unsigned short* __restrict__ Vt,
                                                  const float* __restrict__ mask,
                                                  const int* __restrict__ flags,
                                                  unsigned short* __restrict__ Op,
                                                  float* __restrict__ Mp,
                                                  float* __restrict__ Lp) {
  const int NBLK = NH * NQB * KVSPLIT;              // 1536
  int id = blockIdx.x;
  int sid = (id & 7) * (NBLK / 8) + (id >> 3);
  const int hh = sid / (NQB * KVSPLIT);
  int rem = sid % (NQB * KVSPLIT);
  const int z  = rem / NQB;
  const int qx = rem % NQB;
  if (!flags[z * NQB + qx]) return;                 // nomask kernel handles this block
  const int q0 = qx * 128;
  const int kv0 = z * KVCHUNK;
  const int NT = KVCHUNK / 64;

  __shared__ unsigned short Ks[2][64 * 64];
  __shared__ unsigned short Vs[2][64 * 64];
  const int lane = threadIdx.x & 63, wv = threadIdx.x >> 6;
  const int q31 = lane & 31, h2 = lane >> 5;
  const int qw = q0 + wv * 32 + q31;

  bf16x8 qf[4];
  #pragma unroll
  for (int ks = 0; ks < 4; ++ks)
    qf[ks] = *(const bf16x8*)(Qh + ((size_t)hh * T_TOK + qw) * HD + ks * 16 + h2 * 8);

  f32x16 acc_o[2] = {};
  float m = -INFINITY, l = 0.f;

  const int ldrow = lane >> 3;
  const int colS  = ((lane & 7) * 16) ^ (ldrow << 4);
  const unsigned short* kga = Kh + ((size_t)hh * T_TOK + wv * 16 + ldrow) * HD + (colS >> 1);
  const unsigned short* vga = Vt + ((size_t)hh * HD + wv * 16 + ldrow) * T_TOK + (colS >> 1);
  char* ksd = (char*)&Ks[0][0] + wv * 2048;
  char* vsd = (char*)&Vs[0][0] + wv * 2048;
  const float* mrow = mask + (size_t)qw * T_TOK;

  auto stage = [&](int buf, int s0) {
    __builtin_amdgcn_global_load_lds(
        (const __attribute__((address_space(1))) unsigned int*)(kga + (size_t)s0 * HD),
        (__attribute__((address_space(3))) unsigned int*)(ksd + buf * 8192), 16, 0, 0);
    __builtin_amdgcn_global_load_lds(
        (const __attribute__((address_space(1))) unsigned int*)(kga + (size_t)s0 * HD + 8 * HD),
        (__attribute__((address_space(3))) unsigned int*)(ksd + buf * 8192 + 1024), 16, 0, 0);
    __builtin_amdgcn_global_load_lds(
        (const __attribute__((address_space(1))) unsigned int*)(vga + s0),
        (__attribute__((address_space(3))) unsigned int*)(vsd + buf * 8192), 16, 0, 0);
    __builtin_amdgcn_global_load_lds(
        (const __attribute__((address_space(1))) unsigned int*)(vga + s0 + 8 * T_TOK),
        (__attribute__((address_space(3))) unsigned int*)(vsd + buf * 8192 + 1024), 16, 0, 0);
  };

  float4 mk[8];

  auto tile_mask = [&](int cur) {
    f32x16 as0 = {}, as1 = {};
    __builtin_amdgcn_s_setprio(1);
    #pragma unroll
    for (int ks = 0; ks < 4; ++ks) {
      bf16x8 kf0 = *(const bf16x8*)&Ks[cur][swz(q31,      ks * 32 + h2 * 16)];
      bf16x8 kf1 = *(const bf16x8*)&Ks[cur][swz(32 + q31, ks * 32 + h2 * 16)];
      as0 = __builtin_amdgcn_mfma_f32_32x32x16_bf16(kf0, qf[ks], as0, 0, 0, 0);
      as1 = __builtin_amdgcn_mfma_f32_32x32x16_bf16(kf1, qf[ks], as1, 0, 0, 0);
    }
    __builtin_amdgcn_s_setprio(0);

    float sv[2][16];
    #pragma unroll
    for (int reg = 0; reg < 16; ++reg) {
      float m0v = (&mk[0 + (reg >> 2)].x)[reg & 3];
      float m1v = (&mk[4 + (reg >> 2)].x)[reg & 3];
      sv[0][reg] = fmaf(m0v, LOG2E, as0[reg]);
      sv[1][reg] = fmaf(m1v, LOG2E, as1[reg]);
    }
    float p0 = sv[0][0];
    #pragma unroll
    for (int i = 1; i < 16; ++i) p0 = fmaxf(p0, sv[0][i]);
    #pragma unroll
    for (int i = 0; i < 16; ++i) p0 = fmaxf(p0, sv[1][i]);
    float pmax = fmaxf(p0, __shfl_xor(p0, 32));
    if (__any(pmax > m + 8.f)) {
      float mnew = fmaxf(m, pmax);
      float sc = __builtin_amdgcn_exp2f(m - mnew);
      m = mnew;
      l *= sc;
      #pragma unroll
      for (int db = 0; db < 2; ++db)
        #pragma unroll
        for (int i = 0; i < 16; ++i) acc_o[db][i] *= sc;
    }
    float ps = 0.f;
    unsigned int pk[16];
    #pragma unroll
    for (int kvb = 0; kvb < 2; ++kvb)
      #pragma unroll
      for (int j = 0; j < 4; ++j) {
        float e0 = __builtin_amdgcn_exp2f(sv[kvb][j * 4 + 0] - m);
        float e1 = __builtin_amdgcn_exp2f(sv[kvb][j * 4 + 1] - m);
        float e2 = __builtin_amdgcn_exp2f(sv[kvb][j * 4 + 2] - m);
        float e3 = __builtin_amdgcn_exp2f(sv[kvb][j * 4 + 3] - m);
        ps += (e0 + e1) + (e2 + e3);
        pk[kvb * 8 + j * 2 + 0] = (unsigned int)f2bf(e0) | ((unsigned int)f2bf(e1) << 16);
        pk[kvb * 8 + j * 2 + 1] = (unsigned int)f2bf(e2) | ((unsigned int)f2bf(e3) << 16);
      }
    l += ps;

    __builtin_amdgcn_s_setprio(1);
    #pragma unroll
    for (int kvb = 0; kvb < 2; ++kvb)
      #pragma unroll
      for (int s = 0; s < 2; ++s) {
        u32x4 fr;
        fr[0] = pk[kvb * 8 + 4 * s + 0];
        fr[1] = pk[kvb * 8 + 4 * s + 1];
        fr[2] = pk[kvb * 8 + 4 * s + 2];
        fr[3] = pk[kvb * 8 + 4 * s + 3];
        bf16x8 pfrag = __builtin_bit_cast(bf16x8, fr);
        #pragma unroll
        for (int db = 0; db < 2; ++db) {
          bf16x8 vf = *(const bf16x8*)&Vs[cur][swz(db * 32 + q31, kvb * 64 + s * 32 + h2 * 16)];
          acc_o[db] = __builtin_amdgcn_mfma_f32_32x32x16_bf16(vf, pfrag, acc_o[db], 0, 0, 0);
        }
      }
    __builtin_amdgcn_s_setprio(0);
  };

  stage(0, kv0);

  for (int it = 0; it < NT - 1; ++it) {
    const int s0 = kv0 + it * 64;
    #pragma unroll
    for (int kvb = 0; kvb < 2; ++kvb)
      #pragma unroll
      for (int g = 0; g < 4; ++g)
        mk[kvb * 4 + g] = *(const float4*)(mrow + s0 + kvb * 32 + g * 8 + 4 * h2);
    stage((it + 1) & 1, s0 + 64);
    VMCNT(12);
    SB();
    __builtin_amdgcn_s_barrier();
    SB();
    tile_mask(it & 1);
    __builtin_amdgcn_s_barrier();
  }
  const int s0l = kv0 + (NT - 1) * 64;
  #pragma unroll
  for (int kvb = 0; kvb < 2; ++kvb)
    #pragma unroll
    for (int g = 0; g < 4; ++g)
      mk[kvb * 4 + g] = *(const float4*)(mrow + s0l + kvb * 32 + g * 8 + 4 * h2);
  VMCNT(8);
  SB();
  __builtin_amdgcn_s_barrier();
  SB();
  tile_mask((NT - 1) & 1);

  float lf = l + __shfl_xor(l, 32);
  float lfinv = 1.f / lf;
  unsigned short* oprow = Op + (((size_t)z * T_TOK + qw) * NH + hh) * HD;
  #pragma unroll
  for (int db = 0; db < 2; ++db)
    #pragma unroll
    for (int g = 0; g < 4; ++g) {
      ushort4 o4;
      o4.x = f2h(acc_o[db][g * 4 + 0] * lfinv);
      o4.y = f2h(acc_o[db][g * 4 + 1] * lfinv);
      o4.z = f2h(acc_o[db][g * 4 + 2] * lfinv);
      o4.w = f2h(acc_o[db][g * 4 + 3] * lfinv);
      *(ushort4*)(oprow + db * 32 + g * 8 + 4 * h2) = o4;
    }
  if (h2 == 0) {
    size_t mi = ((size_t)z * T_TOK + qw) * NH + hh;
    Mp[mi] = m;
    Lp[mi] = lf;
  }
}

// ---------------- combine KV-split partials (normalized f16 Op) ----------------
__global__ __launch_bounds__(256) void combine(const unsigned short* __restrict__ Op,
                                               const float* __restrict__ Mp,
                                               const float* __restrict__ Lp,
                                               unsigned short* __restrict__ Ob) {
  int idx = blockIdx.x * 256 + threadIdx.x;
  int t = idx >> 8;
  int q4 = (idx & 255) * 4;
  int h = q4 >> 6, d = q4 & 63;
  float mz[KVSPLIT], lz[KVSPLIT];
  float ms = -INFINITY;
  #pragma unroll
  for (int zz = 0; zz < KVSPLIT; ++zz) {
    size_t mi = ((size_t)zz * T_TOK + t) * NH + h;
    mz[zz] = Mp[mi];
    lz[zz] = Lp[mi];
    ms = fmaxf(ms, mz[zz]);
  }
  float lsum = 0.f;
  float wl[KVSPLIT];
  #pragma unroll
  for (int zz = 0; zz < KVSPLIT; ++zz) {
    wl[zz] = lz[zz] * __builtin_amdgcn_exp2f(mz[zz] - ms);
    lsum += wl[zz];
  }
  float4 o = {0.f, 0.f, 0.f, 0.f};
  #pragma unroll
  for (int zz = 0; zz < KVSPLIT; ++zz) {
    ushort4 p = *(const ushort4*)(Op + (((size_t)zz * T_TOK + t) * NH + h) * HD + d);
    o.x += h2f(p.x) * wl[zz]; o.y += h2f(p.y) * wl[zz];
    o.z += h2f(p.z) * wl[zz]; o.w += h2f(p.w) * wl[zz];
  }
  float inv = 1.f / lsum;
  ushort4 ob;
  ob.x = f2bf(o.x * inv); ob.y = f2bf(o.y * inv);
  ob.z = f2bf(o.z * inv); ob.w = f2bf(o.w * inv);
  *(ushort4*)(Ob + (size_t)t * HID + q4) = ob;
}

extern "C" void kernel_launch(void* const* d_in, const int* in_sizes, int n_in,
                              void* d_out, int out_size, void* d_ws, size_t ws_size,
                              hipStream_t stream) {
  const float* X    = (const float*)d_in[0];
  const float* Wqkv = (const float*)d_in[1];
  const float* Wo   = (const float*)d_in[2];
  const float* mask = (const float*)d_in[3];
  const int*   pos  = (const int*)d_in[4];
  float* out = (float*)d_out;

  char* ws = (char*)d_ws;
  size_t off = 0;
  auto alloc = [&](size_t bytes) {
    char* p = ws + off;
    off += (bytes + 255) & ~(size_t)255;
    return p;
  };
  unsigned short* Xb    = (unsigned short*)alloc((size_t)T_TOK * HID * 2);
  unsigned short* WqkvT = (unsigned short*)alloc((size_t)3 * HID * HID * 2);
  unsigned short* WoT   = (unsigned short*)alloc((size_t)HID * HID * 2);
  unsigned short* Qh    = (unsigned short*)alloc((size_t)NH * T_TOK * HD * 2);
  unsigned short* Kh    = (unsigned short*)alloc((size_t)NH * T_TOK * HD * 2);
  unsigned short* Vt    = (unsigned short*)alloc((size_t)NH * HD * T_TOK * 2);
  unsigned short* Ob    = (unsigned short*)alloc((size_t)T_TOK * HID * 2);
  float*          ctab  = (float*)alloc((size_t)T_TOK * 32 * 4);
  float*          stab  = (float*)alloc((size_t)T_TOK * 32 * 4);
  float*          Mp    = (float*)alloc((size_t)KVSPLIT * T_TOK * NH * 4);
  float*          Lp    = (float*)alloc((size_t)KVSPLIT * T_TOK * NH * 4);
  int*            flags = (int*)alloc((size_t)KVSPLIT * NQB * 4);
  // REGION: bf16 QKV (18.9MB) aliased with f16 Opart (KVSPLIT x T x HID x 2B = 25.2MB).
  char*           region = alloc((size_t)KVSPLIT * T_TOK * HID * 2);
  unsigned short* QKVb  = (unsigned short*)region;
  unsigned short* Op    = (unsigned short*)region;

  prep<<<7648, 256, 0, stream>>>(X, Wqkv, Wo, pos, mask, Xb, WqkvT, WoT, ctab, stab, flags);

  gemm_bt_bf16<<<dim3((3 * HID / 128) * (T_TOK / 128)), 256, 0, stream>>>(Xb, WqkvT, QKVb, T_TOK, 3 * HID, HID);

  rope_v<<<dim3(T_TOK / 64, NH), 256, 0, stream>>>(QKVb, ctab, stab, Qh, Kh, Vt);

  flash_nomask<<<dim3(NH * NQB * KVSPLIT), 256, 0, stream>>>(Qh, Kh, Vt, flags, Op, Mp, Lp);
  flash_mask<<<dim3(NH * NQB * KVSPLIT), 256, 0, stream>>>(Qh, Kh, Vt, mask, flags, Op, Mp, Lp);
  combine<<<T_TOK, 256, 0, stream>>>(Op, Mp, Lp, Ob);

  gemm_bt<<<dim3((HID / 128) * (T_TOK / 128)), 256, 0, stream>>>(Ob, WoT, out, T_TOK, HID, HID);
}

// Round 16
// 156.230 us; speedup vs baseline: 1.2463x; 1.2463x over previous
//
#include <hip/hip_runtime.h>
#include <hip/hip_bf16.h>
#include <hip/hip_fp16.h>
#include <math.h>

#define T_TOK 3072
#define HID   1024
#define NH    16
#define HD    64
#define KVSPLIT 4
#define KVCHUNK (T_TOK / KVSPLIT)   // 768
#define NQB (T_TOK / 128)           // 24 q-tiles of 128 rows
#define LOG2E 1.4426950408889634f

typedef __attribute__((ext_vector_type(8))) short bf16x8;
typedef __attribute__((ext_vector_type(8))) unsigned short u16x8;
typedef __attribute__((ext_vector_type(4))) float f32x4;
typedef __attribute__((ext_vector_type(16))) float f32x16;
typedef __attribute__((ext_vector_type(4))) unsigned int u32x4;

#define VMCNT(n) asm volatile("s_waitcnt vmcnt(" #n ")" ::: "memory")
#define SB() __builtin_amdgcn_sched_barrier(0)

static __device__ __forceinline__ unsigned short f2bf(float x) {
  __hip_bfloat16 h = __float2bfloat16(x);
  return __builtin_bit_cast(unsigned short, h);
}
static __device__ __forceinline__ float bf2f(unsigned short u) {
  unsigned int v = (unsigned int)u << 16;
  return __builtin_bit_cast(float, v);
}
static __device__ __forceinline__ unsigned short f2h(float x) {
  __half h = __float2half(x);
  return __builtin_bit_cast(unsigned short, h);
}
static __device__ __forceinline__ float h2f(unsigned short u) {
  __half h = __builtin_bit_cast(__half, u);
  return __half2float(h);
}
// fast bf16 pair pack, round-half-up (P >= 0, never NaN): ~4 VALU per pair
static __device__ __forceinline__ unsigned int pack_bf16(float a, float b) {
  unsigned int ua = __builtin_bit_cast(unsigned int, a) + 0x8000u;
  unsigned int ub = __builtin_bit_cast(unsigned int, b) + 0x8000u;
  return (ua >> 16) | (ub & 0xffff0000u);
}

// swizzled LDS short-index for a [rows][64 bf16] tile, row stride 128B (flash).
static __device__ __forceinline__ int swz(int row, int cb) {
  return row * 64 + ((cb ^ ((row & 7) << 4)) >> 1);
}

// ---------------- merged preprocessing (block-range dispatch) ----------------
__global__ __launch_bounds__(256) void prep(const float* __restrict__ X,
                                            const float* __restrict__ Wqkv,
                                            const float* __restrict__ Wo,
                                            const int* __restrict__ pos,
                                            const float* __restrict__ mask,
                                            unsigned short* __restrict__ Xb,
                                            unsigned short* __restrict__ WqkvT,
                                            unsigned short* __restrict__ WoT,
                                            float* __restrict__ ctab,
                                            float* __restrict__ stab,
                                            int* __restrict__ flags) {
  __shared__ float tile[32][33];
  __shared__ int sflag;
  const int b = blockIdx.x;
  const int tid = threadIdx.x;
  if (b < 3072) {
    int i = (b * 256 + tid) * 4;
    float4 v = *(const float4*)(X + i);
    ushort4 o;
    o.x = f2bf(v.x); o.y = f2bf(v.y); o.z = f2bf(v.z); o.w = f2bf(v.w);
    *(ushort4*)(Xb + i) = o;
  } else if (b < 6144) {
    int b2 = b - 3072;
    int c0 = (b2 % 96) * 32, r0 = (b2 / 96) * 32;
    int tx = tid & 31, ty = tid >> 5;
    #pragma unroll
    for (int i2 = 0; i2 < 32; i2 += 8)
      tile[ty + i2][tx] = Wqkv[(size_t)(r0 + ty + i2) * 3072 + c0 + tx];
    __syncthreads();
    #pragma unroll
    for (int i2 = 0; i2 < 32; i2 += 8)
      WqkvT[(size_t)(c0 + ty + i2) * 1024 + r0 + tx] = f2bf(tile[tx][ty + i2]);
  } else if (b < 7168) {
    int b2 = b - 6144;
    int c0 = (b2 % 32) * 32, r0 = (b2 / 32) * 32;
    int tx = tid & 31, ty = tid >> 5;
    #pragma unroll
    for (int i2 = 0; i2 < 32; i2 += 8)
      tile[ty + i2][tx] = Wo[(size_t)(r0 + ty + i2) * 1024 + c0 + tx];
    __syncthreads();
    #pragma unroll
    for (int i2 = 0; i2 < 32; i2 += 8)
      WoT[(size_t)(c0 + ty + i2) * 1024 + r0 + tx] = f2bf(tile[tx][ty + i2]);
  } else if (b < 7552) {
    int i = (b - 7168) * 256 + tid;   // T*32
    int t = i >> 5, j = i & 31;
    float inv = expf(-(float)j * 0.28782313662425572f);  // 10000^(-j/32)
    float f = (float)pos[t] * inv;
    ctab[i] = cosf(f);
    stab[i] = sinf(f);
  } else {
    int c = b - 7552;                 // 96 chunks
    int qx = c % NQB, z = c / NQB;
    const float* base = mask + (size_t)(qx * 128) * T_TOK + z * KVCHUNK;
    int any = 0;
    const int NC4 = KVCHUNK / 4;      // 192
    for (int i = tid; i < 128 * NC4; i += 256) {
      int row = i / NC4, cc = i - row * NC4;
      float4 v = *(const float4*)(base + (size_t)row * T_TOK + cc * 4);
      any |= (v.x != 0.f) | (v.y != 0.f) | (v.z != 0.f) | (v.w != 0.f);
    }
    if (tid == 0) sflag = 0;
    __syncthreads();
    if (__any(any) && (tid & 63) == 0) sflag = 1;  // benign same-value race
    __syncthreads();
    if (tid == 0) flags[z * NQB + qx] = sflag;
  }
}

// ---------------- fused RoPE split + V transpose (reads bf16 QKV once) ----------------
// V^T stored PERMUTED (swap bits 2<->3 of token-within-16) -> flash PV is
// shuffle-free with a single b128 LDS read per fragment.
__global__ __launch_bounds__(256) void rope_v(const unsigned short* __restrict__ QKVb,
                                              const float* __restrict__ ctab,
                                              const float* __restrict__ stab,
                                              unsigned short* __restrict__ Qh,
                                              unsigned short* __restrict__ Kh,
                                              unsigned short* __restrict__ Vt) {
  const float QSCL = 0.18033688011112042f;  // 0.125 * log2e
  const int h = blockIdx.y;
  const int t0 = blockIdx.x * 64;
  const int g = threadIdx.x & 3, tl = threadIdx.x >> 2;
  const int t = t0 + tl;
  __shared__ unsigned short vlds[64][72];

  const size_t rowb = (size_t)t * (3 * HID) + h * HD + g * 8;
  u16x8 qa = *(const u16x8*)(QKVb + rowb);
  u16x8 qb = *(const u16x8*)(QKVb + rowb + 32);
  u16x8 ka = *(const u16x8*)(QKVb + rowb + HID);
  u16x8 kb = *(const u16x8*)(QKVb + rowb + HID + 32);
  u16x8 va = *(const u16x8*)(QKVb + rowb + 2 * HID);
  u16x8 vb = *(const u16x8*)(QKVb + rowb + 2 * HID + 32);

  u16x8 qo0, qo1, ko0, ko1;
  #pragma unroll
  for (int e = 0; e < 8; ++e) {
    int j = g * 8 + e;
    float c = ctab[t * 32 + j], s = stab[t * 32 + j];
    float q1 = bf2f(qa[e]), q2 = bf2f(qb[e]);
    float k1 = bf2f(ka[e]), k2 = bf2f(kb[e]);
    qo0[e] = f2bf((q1 * c - q2 * s) * QSCL);
    qo1[e] = f2bf((q2 * c + q1 * s) * QSCL);
    ko0[e] = f2bf(k1 * c - k2 * s);
    ko1[e] = f2bf(k2 * c + k1 * s);
    vlds[tl][j] = va[e];
    vlds[tl][32 + j] = vb[e];
  }
  size_t ob = ((size_t)h * T_TOK + t) * HD + g * 8;
  *(u16x8*)(Qh + ob) = qo0;
  *(u16x8*)(Qh + ob + 32) = qo1;
  *(u16x8*)(Kh + ob) = ko0;
  *(u16x8*)(Kh + ob + 32) = ko1;

  __syncthreads();
  u16x8 o0, o1;
  #pragma unroll
  for (int e = 0; e < 8; ++e) {
    o0[e] = vlds[g * 16 + e][tl];
    o1[e] = vlds[g * 16 + 8 + e][tl];
  }
  u16x8 w0, w1;
  #pragma unroll
  for (int e = 0; e < 4; ++e) {
    w0[e] = o0[e];     w0[4 + e] = o1[e];
    w1[e] = o0[4 + e]; w1[4 + e] = o1[4 + e];
  }
  size_t vb2 = ((size_t)h * HD + tl) * T_TOK + t0 + g * 16;
  *(u16x8*)(Vt + vb2) = w0;
  *(u16x8*)(Vt + vb2 + 8) = w1;
}

// ---------------- GEMM: counted-vmcnt double-buffered pipeline (R12-proven) ----------------
template <int OBF16>
__device__ __forceinline__ void gemm_body(const unsigned short* __restrict__ A,
                                          const unsigned short* __restrict__ Bt,
                                          float* __restrict__ C,
                                          unsigned short* __restrict__ Cb,
                                          int M, int N, int K) {
  __shared__ unsigned short As[2][128 * 32];
  __shared__ unsigned short Bs[2][128 * 32];
  const int lane = threadIdx.x & 63;
  const int wv = threadIdx.x >> 6;
  const int wm = wv >> 1, wn = wv & 1;
  const int r = lane & 15, hi = lane >> 4;
  const int nwg = gridDim.x;                       // divisible by 8
  const int flat = blockIdx.x;
  const int sid = (flat & 7) * (nwg >> 3) + (flat >> 3);
  const int mblocks = M >> 7;
  const int m0 = (sid % mblocks) * 128, n0 = (sid / mblocks) * 128;

  const int srow = lane >> 2;                          // 0..15
  const int scb  = ((lane & 3) * 16) ^ ((srow & 3) << 4);
  const unsigned short* ga = A  + (size_t)(m0 + wv * 16 + srow) * K + (scb >> 1);
  const unsigned short* gb = Bt + (size_t)(n0 + wv * 16 + srow) * K + (scb >> 1);
  char* asd = (char*)&As[0][0] + wv * 1024;
  char* bsd = (char*)&Bs[0][0] + wv * 1024;

  auto stage = [&](int buf, int kt) {
    __builtin_amdgcn_global_load_lds(
        (const __attribute__((address_space(1))) unsigned int*)(ga + kt),
        (__attribute__((address_space(3))) unsigned int*)(asd + buf * 8192), 16, 0, 0);
    __builtin_amdgcn_global_load_lds(
        (const __attribute__((address_space(1))) unsigned int*)(ga + (size_t)64 * K + kt),
        (__attribute__((address_space(3))) unsigned int*)(asd + buf * 8192 + 4096), 16, 0, 0);
    __builtin_amdgcn_global_load_lds(
        (const __attribute__((address_space(1))) unsigned int*)(gb + kt),
        (__attribute__((address_space(3))) unsigned int*)(bsd + buf * 8192), 16, 0, 0);
    __builtin_amdgcn_global_load_lds(
        (const __attribute__((address_space(1))) unsigned int*)(gb + (size_t)64 * K + kt),
        (__attribute__((address_space(3))) unsigned int*)(bsd + buf * 8192 + 4096), 16, 0, 0);
  };

  f32x4 acc[4][4] = {};
  const int NT = K >> 5;
  stage(0, 0);
  #pragma unroll 2
  for (int it = 0; it < NT; ++it) {
    const int buf = it & 1;
    if (it + 1 < NT) {
      stage(buf ^ 1, (it + 1) * 32);
      VMCNT(4);
    } else {
      VMCNT(0);
    }
    SB();
    __builtin_amdgcn_s_barrier();
    SB();
    bf16x8 a[4], b[4];
    const int cbs = (hi * 16) ^ ((r & 3) << 4);
    #pragma unroll
    for (int tm = 0; tm < 4; ++tm)
      a[tm] = *(const bf16x8*)&As[buf][(wm * 64 + tm * 16 + r) * 32 + (cbs >> 1)];
    #pragma unroll
    for (int tn = 0; tn < 4; ++tn)
      b[tn] = *(const bf16x8*)&Bs[buf][(wn * 64 + tn * 16 + r) * 32 + (cbs >> 1)];
    #pragma unroll
    for (int tm = 0; tm < 4; ++tm)
      #pragma unroll
      for (int tn = 0; tn < 4; ++tn)
        acc[tm][tn] = __builtin_amdgcn_mfma_f32_16x16x32_bf16(a[tm], b[tn], acc[tm][tn], 0, 0, 0);
    __builtin_amdgcn_s_barrier();
  }
  #pragma unroll
  for (int tm = 0; tm < 4; ++tm)
    #pragma unroll
    for (int tn = 0; tn < 4; ++tn) {
      int colg = n0 + wn * 64 + tn * 16 + r;
      int rowg = m0 + wm * 64 + tm * 16 + hi * 4;
      if (OBF16) {
        unsigned short* cp = Cb + (size_t)rowg * N + colg;
        #pragma unroll
        for (int j = 0; j < 4; ++j) cp[(size_t)j * N] = f2bf(acc[tm][tn][j]);
      } else {
        float* cp = C + (size_t)rowg * N + colg;
        #pragma unroll
        for (int j = 0; j < 4; ++j) cp[(size_t)j * N] = acc[tm][tn][j];
      }
    }
}

__global__ __launch_bounds__(256) void gemm_bt(const unsigned short* __restrict__ A,
                                               const unsigned short* __restrict__ Bt,
                                               float* __restrict__ C, int M, int N, int K) {
  gemm_body<0>(A, Bt, C, nullptr, M, N, K);
}
__global__ __launch_bounds__(256) void gemm_bt_bf16(const unsigned short* __restrict__ A,
                                                    const unsigned short* __restrict__ Bt,
                                                    unsigned short* __restrict__ Cb,
                                                    int M, int N, int K) {
  gemm_body<1>(A, Bt, nullptr, Cb, M, N, K);
}

// ---------------- flash attention (R13 structure; fast bf16 pack) ----------------
// No-mask path: fixed softmax base m=0 (scores bounded; P=exp2(S)<=2^9,
// l<=3072*2^9 f32-exact). Mask path: full online softmax.
__global__ __launch_bounds__(256) void flash_attn(const unsigned short* __restrict__ Qh,
                                                  const unsigned short* __restrict__ Kh,
                                                  const unsigned short* __restrict__ Vt,
                                                  const float* __restrict__ mask,
                                                  const int* __restrict__ flags,
                                                  unsigned short* __restrict__ Op,
                                                  float* __restrict__ Mp,
                                                  float* __restrict__ Lp) {
  const int NBLK = NH * NQB * KVSPLIT;              // 1536
  int id = blockIdx.x;
  int sid = (id & 7) * (NBLK / 8) + (id >> 3);      // XCD gets contiguous sid chunk
  const int hh = sid / (NQB * KVSPLIT);             // h slowest: 2 heads per XCD
  int rem = sid % (NQB * KVSPLIT);
  const int z  = rem / NQB;
  const int qx = rem % NQB;
  const int q0 = qx * 128;
  const int kv0 = z * KVCHUNK;
  const int NT = KVCHUNK / 64;                      // 12

  __shared__ unsigned short Ks[2][64 * 64];
  __shared__ unsigned short Vs[2][64 * 64];
  const int lane = threadIdx.x & 63, wv = threadIdx.x >> 6;
  const int q31 = lane & 31, h2 = lane >> 5;
  const int qw = q0 + wv * 32 + q31;

  bf16x8 qf[4];
  #pragma unroll
  for (int ks = 0; ks < 4; ++ks)
    qf[ks] = *(const bf16x8*)(Qh + ((size_t)hh * T_TOK + qw) * HD + ks * 16 + h2 * 8);

  f32x16 acc_o[2] = {};
  const int hasmask = flags[z * NQB + qx];
  float m = hasmask ? -INFINITY : 0.f;
  float l = 0.f;

  const int ldrow = lane >> 3;
  const int colS  = ((lane & 7) * 16) ^ (ldrow << 4);
  const unsigned short* kga = Kh + ((size_t)hh * T_TOK + wv * 16 + ldrow) * HD + (colS >> 1);
  const unsigned short* vga = Vt + ((size_t)hh * HD + wv * 16 + ldrow) * T_TOK + (colS >> 1);
  char* ksd = (char*)&Ks[0][0] + wv * 2048;
  char* vsd = (char*)&Vs[0][0] + wv * 2048;
  const float* mrow = mask + (size_t)qw * T_TOK;

  auto stage = [&](int buf, int s0) {
    __builtin_amdgcn_global_load_lds(
        (const __attribute__((address_space(1))) unsigned int*)(kga + (size_t)s0 * HD),
        (__attribute__((address_space(3))) unsigned int*)(ksd + buf * 8192), 16, 0, 0);
    __builtin_amdgcn_global_load_lds(
        (const __attribute__((address_space(1))) unsigned int*)(kga + (size_t)s0 * HD + 8 * HD),
        (__attribute__((address_space(3))) unsigned int*)(ksd + buf * 8192 + 1024), 16, 0, 0);
    __builtin_amdgcn_global_load_lds(
        (const __attribute__((address_space(1))) unsigned int*)(vga + s0),
        (__attribute__((address_space(3))) unsigned int*)(vsd + buf * 8192), 16, 0, 0);
    __builtin_amdgcn_global_load_lds(
        (const __attribute__((address_space(1))) unsigned int*)(vga + s0 + 8 * T_TOK),
        (__attribute__((address_space(3))) unsigned int*)(vsd + buf * 8192 + 1024), 16, 0, 0);
  };

  float4 mk[8];

  auto qkt = [&](int cur, f32x16& as0, f32x16& as1) {
    __builtin_amdgcn_s_setprio(1);
    #pragma unroll
    for (int ks = 0; ks < 4; ++ks) {
      bf16x8 kf0 = *(const bf16x8*)&Ks[cur][swz(q31,      ks * 32 + h2 * 16)];
      bf16x8 kf1 = *(const bf16x8*)&Ks[cur][swz(32 + q31, ks * 32 + h2 * 16)];
      as0 = __builtin_amdgcn_mfma_f32_32x32x16_bf16(kf0, qf[ks], as0, 0, 0, 0);
      as1 = __builtin_amdgcn_mfma_f32_32x32x16_bf16(kf1, qf[ks], as1, 0, 0, 0);
    }
    __builtin_amdgcn_s_setprio(0);
  };

  auto pv = [&](int cur, const unsigned int* pk) {
    __builtin_amdgcn_s_setprio(1);
    #pragma unroll
    for (int kvb = 0; kvb < 2; ++kvb)
      #pragma unroll
      for (int s = 0; s < 2; ++s) {
        u32x4 fr;
        fr[0] = pk[kvb * 8 + 4 * s + 0];
        fr[1] = pk[kvb * 8 + 4 * s + 1];
        fr[2] = pk[kvb * 8 + 4 * s + 2];
        fr[3] = pk[kvb * 8 + 4 * s + 3];
        bf16x8 pfrag = __builtin_bit_cast(bf16x8, fr);
        #pragma unroll
        for (int db = 0; db < 2; ++db) {
          bf16x8 vf = *(const bf16x8*)&Vs[cur][swz(db * 32 + q31, kvb * 64 + s * 32 + h2 * 16)];
          acc_o[db] = __builtin_amdgcn_mfma_f32_32x32x16_bf16(vf, pfrag, acc_o[db], 0, 0, 0);
        }
      }
    __builtin_amdgcn_s_setprio(0);
  };

  auto tile_nomask = [&](int cur) {
    f32x16 as0 = {}, as1 = {};
    qkt(cur, as0, as1);
    float ps = 0.f;
    unsigned int pk[16];
    #pragma unroll
    for (int kvb = 0; kvb < 2; ++kvb) {
      const f32x16& as = kvb ? as1 : as0;
      #pragma unroll
      for (int j = 0; j < 4; ++j) {
        float e0 = __builtin_amdgcn_exp2f(as[j * 4 + 0]);
        float e1 = __builtin_amdgcn_exp2f(as[j * 4 + 1]);
        float e2 = __builtin_amdgcn_exp2f(as[j * 4 + 2]);
        float e3 = __builtin_amdgcn_exp2f(as[j * 4 + 3]);
        ps += (e0 + e1) + (e2 + e3);
        pk[kvb * 8 + j * 2 + 0] = pack_bf16(e0, e1);
        pk[kvb * 8 + j * 2 + 1] = pack_bf16(e2, e3);
      }
    }
    l += ps;
    pv(cur, pk);
  };

  auto tile_mask = [&](int cur) {
    f32x16 as0 = {}, as1 = {};
    qkt(cur, as0, as1);
    float sv[2][16];
    #pragma unroll
    for (int reg = 0; reg < 16; ++reg) {
      float m0v = (&mk[0 + (reg >> 2)].x)[reg & 3];
      float m1v = (&mk[4 + (reg >> 2)].x)[reg & 3];
      sv[0][reg] = fmaf(m0v, LOG2E, as0[reg]);
      sv[1][reg] = fmaf(m1v, LOG2E, as1[reg]);
    }
    float p0 = sv[0][0];
    #pragma unroll
    for (int i = 1; i < 16; ++i) p0 = fmaxf(p0, sv[0][i]);
    #pragma unroll
    for (int i = 0; i < 16; ++i) p0 = fmaxf(p0, sv[1][i]);
    float pmax = fmaxf(p0, __shfl_xor(p0, 32));
    if (__any(pmax > m + 8.f)) {
      float mnew = fmaxf(m, pmax);
      float sc = __builtin_amdgcn_exp2f(m - mnew);
      m = mnew;
      l *= sc;
      #pragma unroll
      for (int db = 0; db < 2; ++db)
        #pragma unroll
        for (int i = 0; i < 16; ++i) acc_o[db][i] *= sc;
    }
    float ps = 0.f;
    unsigned int pk[16];
    #pragma unroll
    for (int kvb = 0; kvb < 2; ++kvb)
      #pragma unroll
      for (int j = 0; j < 4; ++j) {
        float e0 = __builtin_amdgcn_exp2f(sv[kvb][j * 4 + 0] - m);
        float e1 = __builtin_amdgcn_exp2f(sv[kvb][j * 4 + 1] - m);
        float e2 = __builtin_amdgcn_exp2f(sv[kvb][j * 4 + 2] - m);
        float e3 = __builtin_amdgcn_exp2f(sv[kvb][j * 4 + 3] - m);
        ps += (e0 + e1) + (e2 + e3);
        pk[kvb * 8 + j * 2 + 0] = pack_bf16(e0, e1);
        pk[kvb * 8 + j * 2 + 1] = pack_bf16(e2, e3);
      }
    l += ps;
    pv(cur, pk);
  };

  stage(0, kv0);  // prologue

  if (hasmask) {
    for (int it = 0; it < NT - 1; ++it) {
      const int s0 = kv0 + it * 64;
      #pragma unroll
      for (int kvb = 0; kvb < 2; ++kvb)
        #pragma unroll
        for (int g = 0; g < 4; ++g)
          mk[kvb * 4 + g] = *(const float4*)(mrow + s0 + kvb * 32 + g * 8 + 4 * h2);
      stage((it + 1) & 1, s0 + 64);
      VMCNT(12);
      SB();
      __builtin_amdgcn_s_barrier();
      SB();
      tile_mask(it & 1);
      __builtin_amdgcn_s_barrier();
    }
    const int s0 = kv0 + (NT - 1) * 64;
    #pragma unroll
    for (int kvb = 0; kvb < 2; ++kvb)
      #pragma unroll
      for (int g = 0; g < 4; ++g)
        mk[kvb * 4 + g] = *(const float4*)(mrow + s0 + kvb * 32 + g * 8 + 4 * h2);
    VMCNT(8);
    SB();
    __builtin_amdgcn_s_barrier();
    SB();
    tile_mask((NT - 1) & 1);
  } else {
    for (int it = 0; it < NT - 1; ++it) {
      stage((it + 1) & 1, kv0 + (it + 1) * 64);
      VMCNT(4);
      SB();
      __builtin_amdgcn_s_barrier();
      SB();
      tile_nomask(it & 1);
      __builtin_amdgcn_s_barrier();
    }
    VMCNT(0);
    SB();
    __builtin_amdgcn_s_barrier();
    SB();
    tile_nomask((NT - 1) & 1);
  }

  // epilogue: normalize by 1/l, store f16 partials
  float lf = l + __shfl_xor(l, 32);
  float lfinv = 1.f / lf;
  unsigned short* oprow = Op + (((size_t)z * T_TOK + qw) * NH + hh) * HD;
  #pragma unroll
  for (int db = 0; db < 2; ++db)
    #pragma unroll
    for (int g = 0; g < 4; ++g) {
      ushort4 o4;
      o4.x = f2h(acc_o[db][g * 4 + 0] * lfinv);
      o4.y = f2h(acc_o[db][g * 4 + 1] * lfinv);
      o4.z = f2h(acc_o[db][g * 4 + 2] * lfinv);
      o4.w = f2h(acc_o[db][g * 4 + 3] * lfinv);
      *(ushort4*)(oprow + db * 32 + g * 8 + 4 * h2) = o4;
    }
  if (h2 == 0) {
    size_t mi = ((size_t)z * T_TOK + qw) * NH + hh;
    Mp[mi] = m;
    Lp[mi] = lf;
  }
}

// ---------------- combine KV-split partials (normalized f16 Op) ----------------
__global__ __launch_bounds__(256) void combine(const unsigned short* __restrict__ Op,
                                               const float* __restrict__ Mp,
                                               const float* __restrict__ Lp,
                                               unsigned short* __restrict__ Ob) {
  int idx = blockIdx.x * 256 + threadIdx.x;
  int t = idx >> 8;
  int q4 = (idx & 255) * 4;
  int h = q4 >> 6, d = q4 & 63;
  float mz[KVSPLIT], lz[KVSPLIT];
  float ms = -INFINITY;
  #pragma unroll
  for (int zz = 0; zz < KVSPLIT; ++zz) {
    size_t mi = ((size_t)zz * T_TOK + t) * NH + h;
    mz[zz] = Mp[mi];
    lz[zz] = Lp[mi];
    ms = fmaxf(ms, mz[zz]);
  }
  float lsum = 0.f;
  float wl[KVSPLIT];
  #pragma unroll
  for (int zz = 0; zz < KVSPLIT; ++zz) {
    wl[zz] = lz[zz] * __builtin_amdgcn_exp2f(mz[zz] - ms);
    lsum += wl[zz];
  }
  float4 o = {0.f, 0.f, 0.f, 0.f};
  #pragma unroll
  for (int zz = 0; zz < KVSPLIT; ++zz) {
    ushort4 p = *(const ushort4*)(Op + (((size_t)zz * T_TOK + t) * NH + h) * HD + d);
    o.x += h2f(p.x) * wl[zz]; o.y += h2f(p.y) * wl[zz];
    o.z += h2f(p.z) * wl[zz]; o.w += h2f(p.w) * wl[zz];
  }
  float inv = 1.f / lsum;
  ushort4 ob;
  ob.x = f2bf(o.x * inv); ob.y = f2bf(o.y * inv);
  ob.z = f2bf(o.z * inv); ob.w = f2bf(o.w * inv);
  *(ushort4*)(Ob + (size_t)t * HID + q4) = ob;
}

extern "C" void kernel_launch(void* const* d_in, const int* in_sizes, int n_in,
                              void* d_out, int out_size, void* d_ws, size_t ws_size,
                              hipStream_t stream) {
  const float* X    = (const float*)d_in[0];
  const float* Wqkv = (const float*)d_in[1];
  const float* Wo   = (const float*)d_in[2];
  const float* mask = (const float*)d_in[3];
  const int*   pos  = (const int*)d_in[4];
  float* out = (float*)d_out;

  char* ws = (char*)d_ws;
  size_t off = 0;
  auto alloc = [&](size_t bytes) {
    char* p = ws + off;
    off += (bytes + 255) & ~(size_t)255;
    return p;
  };
  unsigned short* Xb    = (unsigned short*)alloc((size_t)T_TOK * HID * 2);
  unsigned short* WqkvT = (unsigned short*)alloc((size_t)3 * HID * HID * 2);
  unsigned short* WoT   = (unsigned short*)alloc((size_t)HID * HID * 2);
  unsigned short* Qh    = (unsigned short*)alloc((size_t)NH * T_TOK * HD * 2);
  unsigned short* Kh    = (unsigned short*)alloc((size_t)NH * T_TOK * HD * 2);
  unsigned short* Vt    = (unsigned short*)alloc((size_t)NH * HD * T_TOK * 2);
  unsigned short* Ob    = (unsigned short*)alloc((size_t)T_TOK * HID * 2);
  float*          ctab  = (float*)alloc((size_t)T_TOK * 32 * 4);
  float*          stab  = (float*)alloc((size_t)T_TOK * 32 * 4);
  float*          Mp    = (float*)alloc((size_t)KVSPLIT * T_TOK * NH * 4);
  float*          Lp    = (float*)alloc((size_t)KVSPLIT * T_TOK * NH * 4);
  int*            flags = (int*)alloc((size_t)KVSPLIT * NQB * 4);
  // REGION: bf16 QKV (18.9MB) aliased with f16 Opart (KVSPLIT x T x HID x 2B = 25.2MB).
  char*           region = alloc((size_t)KVSPLIT * T_TOK * HID * 2);
  unsigned short* QKVb  = (unsigned short*)region;
  unsigned short* Op    = (unsigned short*)region;

  prep<<<7648, 256, 0, stream>>>(X, Wqkv, Wo, pos, mask, Xb, WqkvT, WoT, ctab, stab, flags);

  gemm_bt_bf16<<<dim3((3 * HID / 128) * (T_TOK / 128)), 256, 0, stream>>>(Xb, WqkvT, QKVb, T_TOK, 3 * HID, HID);

  rope_v<<<dim3(T_TOK / 64, NH), 256, 0, stream>>>(QKVb, ctab, stab, Qh, Kh, Vt);

  flash_attn<<<dim3(NH * NQB * KVSPLIT), 256, 0, stream>>>(Qh, Kh, Vt, mask, flags, Op, Mp, Lp);
  combine<<<T_TOK, 256, 0, stream>>>(Op, Mp, Lp, Ob);

  gemm_bt<<<dim3((HID / 128) * (T_TOK / 128)), 256, 0, stream>>>(Ob, WoT, out, T_TOK, HID, HID);
}

// Round 17
// 152.098 us; speedup vs baseline: 1.2802x; 1.0272x over previous
//
#include <hip/hip_runtime.h>
#include <hip/hip_bf16.h>
#include <hip/hip_fp16.h>
#include <math.h>

#define T_TOK 3072
#define HID   1024
#define NH    16
#define HD    64
#define KVSPLIT 4
#define KVCHUNK (T_TOK / KVSPLIT)   // 768
#define NQB (T_TOK / 128)           // 24 q-tiles of 128 rows
#define LOG2E 1.4426950408889634f

typedef __attribute__((ext_vector_type(8))) short bf16x8;
typedef __attribute__((ext_vector_type(8))) unsigned short u16x8;
typedef __attribute__((ext_vector_type(4))) float f32x4;
typedef __attribute__((ext_vector_type(16))) float f32x16;
typedef __attribute__((ext_vector_type(4))) unsigned int u32x4;

#define VMCNT(n) asm volatile("s_waitcnt vmcnt(" #n ")" ::: "memory")
#define SB() __builtin_amdgcn_sched_barrier(0)

static __device__ __forceinline__ unsigned short f2bf(float x) {
  __hip_bfloat16 h = __float2bfloat16(x);
  return __builtin_bit_cast(unsigned short, h);
}
static __device__ __forceinline__ float bf2f(unsigned short u) {
  unsigned int v = (unsigned int)u << 16;
  return __builtin_bit_cast(float, v);
}
static __device__ __forceinline__ unsigned short f2h(float x) {
  __half h = __float2half(x);
  return __builtin_bit_cast(unsigned short, h);
}
static __device__ __forceinline__ float h2f(unsigned short u) {
  __half h = __builtin_bit_cast(__half, u);
  return __half2float(h);
}
// fast bf16 pair pack, round-half-up (P >= 0, never NaN): ~4 VALU per pair
static __device__ __forceinline__ unsigned int pack_bf16(float a, float b) {
  unsigned int ua = __builtin_bit_cast(unsigned int, a) + 0x8000u;
  unsigned int ub = __builtin_bit_cast(unsigned int, b) + 0x8000u;
  return (ua >> 16) | (ub & 0xffff0000u);
}

// swizzled LDS short-index for a [rows][64 bf16] tile, row stride 128B (flash).
static __device__ __forceinline__ int swz(int row, int cb) {
  return row * 64 + ((cb ^ ((row & 7) << 4)) >> 1);
}

// ---------------- merged preprocessing (block-range dispatch) ----------------
__global__ __launch_bounds__(256) void prep(const float* __restrict__ X,
                                            const float* __restrict__ Wqkv,
                                            const float* __restrict__ Wo,
                                            const int* __restrict__ pos,
                                            const float* __restrict__ mask,
                                            unsigned short* __restrict__ Xb,
                                            unsigned short* __restrict__ WqkvT,
                                            unsigned short* __restrict__ WoT,
                                            float* __restrict__ ctab,
                                            float* __restrict__ stab,
                                            int* __restrict__ flags) {
  __shared__ float tile[32][33];
  __shared__ int sflag;
  const int b = blockIdx.x;
  const int tid = threadIdx.x;
  if (b < 3072) {
    int i = (b * 256 + tid) * 4;
    float4 v = *(const float4*)(X + i);
    ushort4 o;
    o.x = f2bf(v.x); o.y = f2bf(v.y); o.z = f2bf(v.z); o.w = f2bf(v.w);
    *(ushort4*)(Xb + i) = o;
  } else if (b < 6144) {
    int b2 = b - 3072;
    int c0 = (b2 % 96) * 32, r0 = (b2 / 96) * 32;
    int tx = tid & 31, ty = tid >> 5;
    #pragma unroll
    for (int i2 = 0; i2 < 32; i2 += 8)
      tile[ty + i2][tx] = Wqkv[(size_t)(r0 + ty + i2) * 3072 + c0 + tx];
    __syncthreads();
    #pragma unroll
    for (int i2 = 0; i2 < 32; i2 += 8)
      WqkvT[(size_t)(c0 + ty + i2) * 1024 + r0 + tx] = f2bf(tile[tx][ty + i2]);
  } else if (b < 7168) {
    int b2 = b - 6144;
    int c0 = (b2 % 32) * 32, r0 = (b2 / 32) * 32;
    int tx = tid & 31, ty = tid >> 5;
    #pragma unroll
    for (int i2 = 0; i2 < 32; i2 += 8)
      tile[ty + i2][tx] = Wo[(size_t)(r0 + ty + i2) * 1024 + c0 + tx];
    __syncthreads();
    #pragma unroll
    for (int i2 = 0; i2 < 32; i2 += 8)
      WoT[(size_t)(c0 + ty + i2) * 1024 + r0 + tx] = f2bf(tile[tx][ty + i2]);
  } else if (b < 7552) {
    int i = (b - 7168) * 256 + tid;   // T*32
    int t = i >> 5, j = i & 31;
    float inv = expf(-(float)j * 0.28782313662425572f);  // 10000^(-j/32)
    float f = (float)pos[t] * inv;
    ctab[i] = cosf(f);
    stab[i] = sinf(f);
  } else {
    int c = b - 7552;                 // 96 chunks
    int qx = c % NQB, z = c / NQB;
    const float* base = mask + (size_t)(qx * 128) * T_TOK + z * KVCHUNK;
    int any = 0;
    const int NC4 = KVCHUNK / 4;      // 192
    for (int i = tid; i < 128 * NC4; i += 256) {
      int row = i / NC4, cc = i - row * NC4;
      float4 v = *(const float4*)(base + (size_t)row * T_TOK + cc * 4);
      any |= (v.x != 0.f) | (v.y != 0.f) | (v.z != 0.f) | (v.w != 0.f);
    }
    if (tid == 0) sflag = 0;
    __syncthreads();
    if (__any(any) && (tid & 63) == 0) sflag = 1;  // benign same-value race
    __syncthreads();
    if (tid == 0) flags[z * NQB + qx] = sflag;
  }
}

// ---------------- fused QKV GEMM + RoPE + V-transpose epilogue ----------------
// C-tile 128x128 never straddles Q/K/V (1024-aligned); each wave's 64-col half
// is one head. RoPE pair (jh, jh+32) = acc regs (tn, tn+2) -- in-register.
// cos/sin tile staged in As/Bs LDS (free after K-loop). V written transposed
// to Vt[h][d][t] at PERMUTED slot (swap token bits 2<->3 within 16-group) so
// flash PV stays shuffle-free.
__global__ __launch_bounds__(256) void gemm_qkv(const unsigned short* __restrict__ A,
                                                const unsigned short* __restrict__ Bt,
                                                const float* __restrict__ ctab,
                                                const float* __restrict__ stab,
                                                unsigned short* __restrict__ Qh,
                                                unsigned short* __restrict__ Kh,
                                                unsigned short* __restrict__ Vt) {
  const int M = T_TOK, N = 3 * HID, K = HID;
  __shared__ unsigned short As[2][128 * 32];
  __shared__ unsigned short Bs[2][128 * 32];
  const int lane = threadIdx.x & 63;
  const int wv = threadIdx.x >> 6;
  const int wm = wv >> 1, wn = wv & 1;
  const int r = lane & 15, hi = lane >> 4;
  const int nwg = gridDim.x;
  const int flat = blockIdx.x;
  const int sid = (flat & 7) * (nwg >> 3) + (flat >> 3);
  const int mblocks = M >> 7;
  const int m0 = (sid % mblocks) * 128, n0 = (sid / mblocks) * 128;

  const int srow = lane >> 2;
  const int scb  = ((lane & 3) * 16) ^ ((srow & 3) << 4);
  const unsigned short* ga = A  + (size_t)(m0 + wv * 16 + srow) * K + (scb >> 1);
  const unsigned short* gb = Bt + (size_t)(n0 + wv * 16 + srow) * K + (scb >> 1);
  char* asd = (char*)&As[0][0] + wv * 1024;
  char* bsd = (char*)&Bs[0][0] + wv * 1024;

  auto stage = [&](int buf, int kt) {
    __builtin_amdgcn_global_load_lds(
        (const __attribute__((address_space(1))) unsigned int*)(ga + kt),
        (__attribute__((address_space(3))) unsigned int*)(asd + buf * 8192), 16, 0, 0);
    __builtin_amdgcn_global_load_lds(
        (const __attribute__((address_space(1))) unsigned int*)(ga + (size_t)64 * K + kt),
        (__attribute__((address_space(3))) unsigned int*)(asd + buf * 8192 + 4096), 16, 0, 0);
    __builtin_amdgcn_global_load_lds(
        (const __attribute__((address_space(1))) unsigned int*)(gb + kt),
        (__attribute__((address_space(3))) unsigned int*)(bsd + buf * 8192), 16, 0, 0);
    __builtin_amdgcn_global_load_lds(
        (const __attribute__((address_space(1))) unsigned int*)(gb + (size_t)64 * K + kt),
        (__attribute__((address_space(3))) unsigned int*)(bsd + buf * 8192 + 4096), 16, 0, 0);
  };

  f32x4 acc[4][4] = {};
  const int NT = K >> 5;
  stage(0, 0);
  #pragma unroll 2
  for (int it = 0; it < NT; ++it) {
    const int buf = it & 1;
    if (it + 1 < NT) {
      stage(buf ^ 1, (it + 1) * 32);
      VMCNT(4);
    } else {
      VMCNT(0);
    }
    SB();
    __builtin_amdgcn_s_barrier();
    SB();
    bf16x8 a[4], b[4];
    const int cbs = (hi * 16) ^ ((r & 3) << 4);
    #pragma unroll
    for (int tm = 0; tm < 4; ++tm)
      a[tm] = *(const bf16x8*)&As[buf][(wm * 64 + tm * 16 + r) * 32 + (cbs >> 1)];
    #pragma unroll
    for (int tn = 0; tn < 4; ++tn)
      b[tn] = *(const bf16x8*)&Bs[buf][(wn * 64 + tn * 16 + r) * 32 + (cbs >> 1)];
    #pragma unroll
    for (int tm = 0; tm < 4; ++tm)
      #pragma unroll
      for (int tn = 0; tn < 4; ++tn)
        acc[tm][tn] = __builtin_amdgcn_mfma_f32_16x16x32_bf16(a[tm], b[tn], acc[tm][tn], 0, 0, 0);
    __builtin_amdgcn_s_barrier();
  }

  const int sec = n0 >> 10;                        // 0=Q, 1=K, 2=V
  const int hh  = ((n0 + wn * 64) >> 6) & 15;      // head (per-wave constant)
  if (sec < 2) {
    // stage cos/sin rows [m0, m0+128) into LDS (reuse As/Bs; 16KB each)
    __syncthreads();
    float* ctl = (float*)&As[0][0];   // [128][32]
    float* stl = (float*)&Bs[0][0];
    for (int i = threadIdx.x; i < 1024; i += 256) {
      ((float4*)ctl)[i] = *(const float4*)(ctab + (size_t)m0 * 32 + i * 4);
      ((float4*)stl)[i] = *(const float4*)(stab + (size_t)m0 * 32 + i * 4);
    }
    __syncthreads();
    const float qscl = (sec == 0) ? 0.18033688011112042f : 1.0f;  // 0.125*log2e on Q
    unsigned short* dst = (sec == 0) ? Qh : Kh;
    #pragma unroll
    for (int tm = 0; tm < 4; ++tm)
      #pragma unroll
      for (int tn2 = 0; tn2 < 2; ++tn2) {
        const int p = tn2 * 16 + r;                // jh in [0,32)
        #pragma unroll
        for (int j = 0; j < 4; ++j) {
          int trow = wm * 64 + tm * 16 + hi * 4 + j;
          float c = ctl[trow * 32 + p], s = stl[trow * 32 + p];
          float q1 = acc[tm][tn2][j], q2 = acc[tm][tn2 + 2][j];
          size_t base = ((size_t)hh * T_TOK + (m0 + trow)) * HD + p;
          dst[base]      = f2bf((q1 * c - q2 * s) * qscl);
          dst[base + 32] = f2bf((q2 * c + q1 * s) * qscl);
        }
      }
  } else {
    // V: transpose + permuted scatter. Token group offset hi*4+j stored at
    // slot hi2*4+j, hi2 = swap of hi's two bits (token bit2<->bit3 swap).
    const int hi2 = ((hi & 1) << 1) | (hi >> 1);
    #pragma unroll
    for (int tn = 0; tn < 4; ++tn) {
      const int d = tn * 16 + r;
      #pragma unroll
      for (int tm = 0; tm < 4; ++tm) {
        int tbase = m0 + wm * 64 + tm * 16 + hi2 * 4;
        ushort4 w;
        w.x = f2bf(acc[tm][tn][0]); w.y = f2bf(acc[tm][tn][1]);
        w.z = f2bf(acc[tm][tn][2]); w.w = f2bf(acc[tm][tn][3]);
        *(ushort4*)(Vt + ((size_t)hh * HD + d) * T_TOK + tbase) = w;
      }
    }
  }
}

// ---------------- GEMM: counted-vmcnt double-buffered pipeline (R12-proven) ----------------
__global__ __launch_bounds__(256) void gemm_bt(const unsigned short* __restrict__ A,
                                               const unsigned short* __restrict__ Bt,
                                               float* __restrict__ C, int M, int N, int K) {
  __shared__ unsigned short As[2][128 * 32];
  __shared__ unsigned short Bs[2][128 * 32];
  const int lane = threadIdx.x & 63;
  const int wv = threadIdx.x >> 6;
  const int wm = wv >> 1, wn = wv & 1;
  const int r = lane & 15, hi = lane >> 4;
  const int nwg = gridDim.x;
  const int flat = blockIdx.x;
  const int sid = (flat & 7) * (nwg >> 3) + (flat >> 3);
  const int mblocks = M >> 7;
  const int m0 = (sid % mblocks) * 128, n0 = (sid / mblocks) * 128;

  const int srow = lane >> 2;
  const int scb  = ((lane & 3) * 16) ^ ((srow & 3) << 4);
  const unsigned short* ga = A  + (size_t)(m0 + wv * 16 + srow) * K + (scb >> 1);
  const unsigned short* gb = Bt + (size_t)(n0 + wv * 16 + srow) * K + (scb >> 1);
  char* asd = (char*)&As[0][0] + wv * 1024;
  char* bsd = (char*)&Bs[0][0] + wv * 1024;

  auto stage = [&](int buf, int kt) {
    __builtin_amdgcn_global_load_lds(
        (const __attribute__((address_space(1))) unsigned int*)(ga + kt),
        (__attribute__((address_space(3))) unsigned int*)(asd + buf * 8192), 16, 0, 0);
    __builtin_amdgcn_global_load_lds(
        (const __attribute__((address_space(1))) unsigned int*)(ga + (size_t)64 * K + kt),
        (__attribute__((address_space(3))) unsigned int*)(asd + buf * 8192 + 4096), 16, 0, 0);
    __builtin_amdgcn_global_load_lds(
        (const __attribute__((address_space(1))) unsigned int*)(gb + kt),
        (__attribute__((address_space(3))) unsigned int*)(bsd + buf * 8192), 16, 0, 0);
    __builtin_amdgcn_global_load_lds(
        (const __attribute__((address_space(1))) unsigned int*)(gb + (size_t)64 * K + kt),
        (__attribute__((address_space(3))) unsigned int*)(bsd + buf * 8192 + 4096), 16, 0, 0);
  };

  f32x4 acc[4][4] = {};
  const int NT = K >> 5;
  stage(0, 0);
  #pragma unroll 2
  for (int it = 0; it < NT; ++it) {
    const int buf = it & 1;
    if (it + 1 < NT) {
      stage(buf ^ 1, (it + 1) * 32);
      VMCNT(4);
    } else {
      VMCNT(0);
    }
    SB();
    __builtin_amdgcn_s_barrier();
    SB();
    bf16x8 a[4], b[4];
    const int cbs = (hi * 16) ^ ((r & 3) << 4);
    #pragma unroll
    for (int tm = 0; tm < 4; ++tm)
      a[tm] = *(const bf16x8*)&As[buf][(wm * 64 + tm * 16 + r) * 32 + (cbs >> 1)];
    #pragma unroll
    for (int tn = 0; tn < 4; ++tn)
      b[tn] = *(const bf16x8*)&Bs[buf][(wn * 64 + tn * 16 + r) * 32 + (cbs >> 1)];
    #pragma unroll
    for (int tm = 0; tm < 4; ++tm)
      #pragma unroll
      for (int tn = 0; tn < 4; ++tn)
        acc[tm][tn] = __builtin_amdgcn_mfma_f32_16x16x32_bf16(a[tm], b[tn], acc[tm][tn], 0, 0, 0);
    __builtin_amdgcn_s_barrier();
  }
  #pragma unroll
  for (int tm = 0; tm < 4; ++tm)
    #pragma unroll
    for (int tn = 0; tn < 4; ++tn) {
      int colg = n0 + wn * 64 + tn * 16 + r;
      int rowg = m0 + wm * 64 + tm * 16 + hi * 4;
      float* cp = C + (size_t)rowg * N + colg;
      #pragma unroll
      for (int j = 0; j < 4; ++j) cp[(size_t)j * N] = acc[tm][tn][j];
    }
}

// ---------------- flash attention (R15 structure, unchanged) ----------------
__global__ __launch_bounds__(256) void flash_attn(const unsigned short* __restrict__ Qh,
                                                  const unsigned short* __restrict__ Kh,
                                                  const unsigned short* __restrict__ Vt,
                                                  const float* __restrict__ mask,
                                                  const int* __restrict__ flags,
                                                  unsigned short* __restrict__ Op,
                                                  float* __restrict__ Mp,
                                                  float* __restrict__ Lp) {
  const int NBLK = NH * NQB * KVSPLIT;              // 1536
  int id = blockIdx.x;
  int sid = (id & 7) * (NBLK / 8) + (id >> 3);      // XCD gets contiguous sid chunk
  const int hh = sid / (NQB * KVSPLIT);             // h slowest: 2 heads per XCD
  int rem = sid % (NQB * KVSPLIT);
  const int z  = rem / NQB;
  const int qx = rem % NQB;
  const int q0 = qx * 128;
  const int kv0 = z * KVCHUNK;
  const int NT = KVCHUNK / 64;                      // 12

  __shared__ unsigned short Ks[2][64 * 64];
  __shared__ unsigned short Vs[2][64 * 64];
  const int lane = threadIdx.x & 63, wv = threadIdx.x >> 6;
  const int q31 = lane & 31, h2 = lane >> 5;
  const int qw = q0 + wv * 32 + q31;

  bf16x8 qf[4];
  #pragma unroll
  for (int ks = 0; ks < 4; ++ks)
    qf[ks] = *(const bf16x8*)(Qh + ((size_t)hh * T_TOK + qw) * HD + ks * 16 + h2 * 8);

  f32x16 acc_o[2] = {};
  const int hasmask = flags[z * NQB + qx];
  float m = hasmask ? -INFINITY : 0.f;
  float l = 0.f;

  const int ldrow = lane >> 3;
  const int colS  = ((lane & 7) * 16) ^ (ldrow << 4);
  const unsigned short* kga = Kh + ((size_t)hh * T_TOK + wv * 16 + ldrow) * HD + (colS >> 1);
  const unsigned short* vga = Vt + ((size_t)hh * HD + wv * 16 + ldrow) * T_TOK + (colS >> 1);
  char* ksd = (char*)&Ks[0][0] + wv * 2048;
  char* vsd = (char*)&Vs[0][0] + wv * 2048;
  const float* mrow = mask + (size_t)qw * T_TOK;

  auto stage = [&](int buf, int s0) {
    __builtin_amdgcn_global_load_lds(
        (const __attribute__((address_space(1))) unsigned int*)(kga + (size_t)s0 * HD),
        (__attribute__((address_space(3))) unsigned int*)(ksd + buf * 8192), 16, 0, 0);
    __builtin_amdgcn_global_load_lds(
        (const __attribute__((address_space(1))) unsigned int*)(kga + (size_t)s0 * HD + 8 * HD),
        (__attribute__((address_space(3))) unsigned int*)(ksd + buf * 8192 + 1024), 16, 0, 0);
    __builtin_amdgcn_global_load_lds(
        (const __attribute__((address_space(1))) unsigned int*)(vga + s0),
        (__attribute__((address_space(3))) unsigned int*)(vsd + buf * 8192), 16, 0, 0);
    __builtin_amdgcn_global_load_lds(
        (const __attribute__((address_space(1))) unsigned int*)(vga + s0 + 8 * T_TOK),
        (__attribute__((address_space(3))) unsigned int*)(vsd + buf * 8192 + 1024), 16, 0, 0);
  };

  float4 mk[8];

  auto qkt = [&](int cur, f32x16& as0, f32x16& as1) {
    __builtin_amdgcn_s_setprio(1);
    #pragma unroll
    for (int ks = 0; ks < 4; ++ks) {
      bf16x8 kf0 = *(const bf16x8*)&Ks[cur][swz(q31,      ks * 32 + h2 * 16)];
      bf16x8 kf1 = *(const bf16x8*)&Ks[cur][swz(32 + q31, ks * 32 + h2 * 16)];
      as0 = __builtin_amdgcn_mfma_f32_32x32x16_bf16(kf0, qf[ks], as0, 0, 0, 0);
      as1 = __builtin_amdgcn_mfma_f32_32x32x16_bf16(kf1, qf[ks], as1, 0, 0, 0);
    }
    __builtin_amdgcn_s_setprio(0);
  };

  auto pv = [&](int cur, const unsigned int* pk) {
    __builtin_amdgcn_s_setprio(1);
    #pragma unroll
    for (int kvb = 0; kvb < 2; ++kvb)
      #pragma unroll
      for (int s = 0; s < 2; ++s) {
        u32x4 fr;
        fr[0] = pk[kvb * 8 + 4 * s + 0];
        fr[1] = pk[kvb * 8 + 4 * s + 1];
        fr[2] = pk[kvb * 8 + 4 * s + 2];
        fr[3] = pk[kvb * 8 + 4 * s + 3];
        bf16x8 pfrag = __builtin_bit_cast(bf16x8, fr);
        #pragma unroll
        for (int db = 0; db < 2; ++db) {
          bf16x8 vf = *(const bf16x8*)&Vs[cur][swz(db * 32 + q31, kvb * 64 + s * 32 + h2 * 16)];
          acc_o[db] = __builtin_amdgcn_mfma_f32_32x32x16_bf16(vf, pfrag, acc_o[db], 0, 0, 0);
        }
      }
    __builtin_amdgcn_s_setprio(0);
  };

  auto tile_nomask = [&](int cur) {
    f32x16 as0 = {}, as1 = {};
    qkt(cur, as0, as1);
    float ps = 0.f;
    unsigned int pk[16];
    #pragma unroll
    for (int kvb = 0; kvb < 2; ++kvb) {
      const f32x16& as = kvb ? as1 : as0;
      #pragma unroll
      for (int j = 0; j < 4; ++j) {
        float e0 = __builtin_amdgcn_exp2f(as[j * 4 + 0]);
        float e1 = __builtin_amdgcn_exp2f(as[j * 4 + 1]);
        float e2 = __builtin_amdgcn_exp2f(as[j * 4 + 2]);
        float e3 = __builtin_amdgcn_exp2f(as[j * 4 + 3]);
        ps += (e0 + e1) + (e2 + e3);
        pk[kvb * 8 + j * 2 + 0] = pack_bf16(e0, e1);
        pk[kvb * 8 + j * 2 + 1] = pack_bf16(e2, e3);
      }
    }
    l += ps;
    pv(cur, pk);
  };

  auto tile_mask = [&](int cur) {
    f32x16 as0 = {}, as1 = {};
    qkt(cur, as0, as1);
    float sv[2][16];
    #pragma unroll
    for (int reg = 0; reg < 16; ++reg) {
      float m0v = (&mk[0 + (reg >> 2)].x)[reg & 3];
      float m1v = (&mk[4 + (reg >> 2)].x)[reg & 3];
      sv[0][reg] = fmaf(m0v, LOG2E, as0[reg]);
      sv[1][reg] = fmaf(m1v, LOG2E, as1[reg]);
    }
    float p0 = sv[0][0];
    #pragma unroll
    for (int i = 1; i < 16; ++i) p0 = fmaxf(p0, sv[0][i]);
    #pragma unroll
    for (int i = 0; i < 16; ++i) p0 = fmaxf(p0, sv[1][i]);
    float pmax = fmaxf(p0, __shfl_xor(p0, 32));
    if (__any(pmax > m + 8.f)) {
      float mnew = fmaxf(m, pmax);
      float sc = __builtin_amdgcn_exp2f(m - mnew);
      m = mnew;
      l *= sc;
      #pragma unroll
      for (int db = 0; db < 2; ++db)
        #pragma unroll
        for (int i = 0; i < 16; ++i) acc_o[db][i] *= sc;
    }
    float ps = 0.f;
    unsigned int pk[16];
    #pragma unroll
    for (int kvb = 0; kvb < 2; ++kvb)
      #pragma unroll
      for (int j = 0; j < 4; ++j) {
        float e0 = __builtin_amdgcn_exp2f(sv[kvb][j * 4 + 0] - m);
        float e1 = __builtin_amdgcn_exp2f(sv[kvb][j * 4 + 1] - m);
        float e2 = __builtin_amdgcn_exp2f(sv[kvb][j * 4 + 2] - m);
        float e3 = __builtin_amdgcn_exp2f(sv[kvb][j * 4 + 3] - m);
        ps += (e0 + e1) + (e2 + e3);
        pk[kvb * 8 + j * 2 + 0] = pack_bf16(e0, e1);
        pk[kvb * 8 + j * 2 + 1] = pack_bf16(e2, e3);
      }
    l += ps;
    pv(cur, pk);
  };

  stage(0, kv0);  // prologue

  if (hasmask) {
    for (int it = 0; it < NT - 1; ++it) {
      const int s0 = kv0 + it * 64;
      #pragma unroll
      for (int kvb = 0; kvb < 2; ++kvb)
        #pragma unroll
        for (int g = 0; g < 4; ++g)
          mk[kvb * 4 + g] = *(const float4*)(mrow + s0 + kvb * 32 + g * 8 + 4 * h2);
      stage((it + 1) & 1, s0 + 64);
      VMCNT(12);
      SB();
      __builtin_amdgcn_s_barrier();
      SB();
      tile_mask(it & 1);
      __builtin_amdgcn_s_barrier();
    }
    const int s0 = kv0 + (NT - 1) * 64;
    #pragma unroll
    for (int kvb = 0; kvb < 2; ++kvb)
      #pragma unroll
      for (int g = 0; g < 4; ++g)
        mk[kvb * 4 + g] = *(const float4*)(mrow + s0 + kvb * 32 + g * 8 + 4 * h2);
    VMCNT(8);
    SB();
    __builtin_amdgcn_s_barrier();
    SB();
    tile_mask((NT - 1) & 1);
  } else {
    for (int it = 0; it < NT - 1; ++it) {
      stage((it + 1) & 1, kv0 + (it + 1) * 64);
      VMCNT(4);
      SB();
      __builtin_amdgcn_s_barrier();
      SB();
      tile_nomask(it & 1);
      __builtin_amdgcn_s_barrier();
    }
    VMCNT(0);
    SB();
    __builtin_amdgcn_s_barrier();
    SB();
    tile_nomask((NT - 1) & 1);
  }

  // epilogue: normalize by 1/l, store f16 partials
  float lf = l + __shfl_xor(l, 32);
  float lfinv = 1.f / lf;
  unsigned short* oprow = Op + (((size_t)z * T_TOK + qw) * NH + hh) * HD;
  #pragma unroll
  for (int db = 0; db < 2; ++db)
    #pragma unroll
    for (int g = 0; g < 4; ++g) {
      ushort4 o4;
      o4.x = f2h(acc_o[db][g * 4 + 0] * lfinv);
      o4.y = f2h(acc_o[db][g * 4 + 1] * lfinv);
      o4.z = f2h(acc_o[db][g * 4 + 2] * lfinv);
      o4.w = f2h(acc_o[db][g * 4 + 3] * lfinv);
      *(ushort4*)(oprow + db * 32 + g * 8 + 4 * h2) = o4;
    }
  if (h2 == 0) {
    size_t mi = ((size_t)z * T_TOK + qw) * NH + hh;
    Mp[mi] = m;
    Lp[mi] = lf;
  }
}

// ---------------- combine KV-split partials (normalized f16 Op) ----------------
__global__ __launch_bounds__(256) void combine(const unsigned short* __restrict__ Op,
                                               const float* __restrict__ Mp,
                                               const float* __restrict__ Lp,
                                               unsigned short* __restrict__ Ob) {
  int idx = blockIdx.x * 256 + threadIdx.x;
  int t = idx >> 8;
  int q4 = (idx & 255) * 4;
  int h = q4 >> 6, d = q4 & 63;
  float mz[KVSPLIT], lz[KVSPLIT];
  float ms = -INFINITY;
  #pragma unroll
  for (int zz = 0; zz < KVSPLIT; ++zz) {
    size_t mi = ((size_t)zz * T_TOK + t) * NH + h;
    mz[zz] = Mp[mi];
    lz[zz] = Lp[mi];
    ms = fmaxf(ms, mz[zz]);
  }
  float lsum = 0.f;
  float wl[KVSPLIT];
  #pragma unroll
  for (int zz = 0; zz < KVSPLIT; ++zz) {
    wl[zz] = lz[zz] * __builtin_amdgcn_exp2f(mz[zz] - ms);
    lsum += wl[zz];
  }
  float4 o = {0.f, 0.f, 0.f, 0.f};
  #pragma unroll
  for (int zz = 0; zz < KVSPLIT; ++zz) {
    ushort4 p = *(const ushort4*)(Op + (((size_t)zz * T_TOK + t) * NH + h) * HD + d);
    o.x += h2f(p.x) * wl[zz]; o.y += h2f(p.y) * wl[zz];
    o.z += h2f(p.z) * wl[zz]; o.w += h2f(p.w) * wl[zz];
  }
  float inv = 1.f / lsum;
  ushort4 ob;
  ob.x = f2bf(o.x * inv); ob.y = f2bf(o.y * inv);
  ob.z = f2bf(o.z * inv); ob.w = f2bf(o.w * inv);
  *(ushort4*)(Ob + (size_t)t * HID + q4) = ob;
}

extern "C" void kernel_launch(void* const* d_in, const int* in_sizes, int n_in,
                              void* d_out, int out_size, void* d_ws, size_t ws_size,
                              hipStream_t stream) {
  const float* X    = (const float*)d_in[0];
  const float* Wqkv = (const float*)d_in[1];
  const float* Wo   = (const float*)d_in[2];
  const float* mask = (const float*)d_in[3];
  const int*   pos  = (const int*)d_in[4];
  float* out = (float*)d_out;

  char* ws = (char*)d_ws;
  size_t off = 0;
  auto alloc = [&](size_t bytes) {
    char* p = ws + off;
    off += (bytes + 255) & ~(size_t)255;
    return p;
  };
  unsigned short* Xb    = (unsigned short*)alloc((size_t)T_TOK * HID * 2);
  unsigned short* WqkvT = (unsigned short*)alloc((size_t)3 * HID * HID * 2);
  unsigned short* WoT   = (unsigned short*)alloc((size_t)HID * HID * 2);
  unsigned short* Qh    = (unsigned short*)alloc((size_t)NH * T_TOK * HD * 2);
  unsigned short* Kh    = (unsigned short*)alloc((size_t)NH * T_TOK * HD * 2);
  unsigned short* Vt    = (unsigned short*)alloc((size_t)NH * HD * T_TOK * 2);
  unsigned short* Ob    = (unsigned short*)alloc((size_t)T_TOK * HID * 2);
  float*          ctab  = (float*)alloc((size_t)T_TOK * 32 * 4);
  float*          stab  = (float*)alloc((size_t)T_TOK * 32 * 4);
  float*          Mp    = (float*)alloc((size_t)KVSPLIT * T_TOK * NH * 4);
  float*          Lp    = (float*)alloc((size_t)KVSPLIT * T_TOK * NH * 4);
  int*            flags = (int*)alloc((size_t)KVSPLIT * NQB * 4);
  unsigned short* Op    = (unsigned short*)alloc((size_t)KVSPLIT * T_TOK * HID * 2);

  prep<<<7648, 256, 0, stream>>>(X, Wqkv, Wo, pos, mask, Xb, WqkvT, WoT, ctab, stab, flags);

  gemm_qkv<<<dim3((3 * HID / 128) * (T_TOK / 128)), 256, 0, stream>>>(Xb, WqkvT, ctab, stab, Qh, Kh, Vt);

  flash_attn<<<dim3(NH * NQB * KVSPLIT), 256, 0, stream>>>(Qh, Kh, Vt, mask, flags, Op, Mp, Lp);
  combine<<<T_TOK, 256, 0, stream>>>(Op, Mp, Lp, Ob);

  gemm_bt<<<dim3((HID / 128) * (T_TOK / 128)), 256, 0, stream>>>(Ob, WoT, out, T_TOK, HID, HID);
}

// Round 18
// 148.471 us; speedup vs baseline: 1.3115x; 1.0244x over previous
//
#include <hip/hip_runtime.h>
#include <hip/hip_bf16.h>
#include <hip/hip_fp16.h>
#include <math.h>

#define T_TOK 3072
#define HID   1024
#define NH    16
#define HD    64
#define KVSPLIT 4
#define KVCHUNK (T_TOK / KVSPLIT)   // 768
#define NQB (T_TOK / 128)           // 24 q-tiles of 128 rows
#define LOG2E 1.4426950408889634f

typedef __attribute__((ext_vector_type(8))) short bf16x8;
typedef __attribute__((ext_vector_type(8))) unsigned short u16x8;
typedef __attribute__((ext_vector_type(4))) float f32x4;
typedef __attribute__((ext_vector_type(16))) float f32x16;
typedef __attribute__((ext_vector_type(4))) unsigned int u32x4;

#define VMCNT(n) asm volatile("s_waitcnt vmcnt(" #n ")" ::: "memory")
#define SB() __builtin_amdgcn_sched_barrier(0)

static __device__ __forceinline__ unsigned short f2bf(float x) {
  __hip_bfloat16 h = __float2bfloat16(x);
  return __builtin_bit_cast(unsigned short, h);
}
static __device__ __forceinline__ float bf2f(unsigned short u) {
  unsigned int v = (unsigned int)u << 16;
  return __builtin_bit_cast(float, v);
}
static __device__ __forceinline__ unsigned short f2h(float x) {
  __half h = __float2half(x);
  return __builtin_bit_cast(unsigned short, h);
}
static __device__ __forceinline__ float h2f(unsigned short u) {
  __half h = __builtin_bit_cast(__half, u);
  return __half2float(h);
}
// fast bf16 pair pack, round-half-up (P >= 0, never NaN): ~4 VALU per pair
static __device__ __forceinline__ unsigned int pack_bf16(float a, float b) {
  unsigned int ua = __builtin_bit_cast(unsigned int, a) + 0x8000u;
  unsigned int ub = __builtin_bit_cast(unsigned int, b) + 0x8000u;
  return (ua >> 16) | (ub & 0xffff0000u);
}

// swizzled LDS short-index for a [rows][64 bf16] tile, row stride 128B (flash).
static __device__ __forceinline__ int swz(int row, int cb) {
  return row * 64 + ((cb ^ ((row & 7) << 4)) >> 1);
}

// ---------------- merged preprocessing (block-range dispatch) ----------------
__global__ __launch_bounds__(256) void prep(const float* __restrict__ X,
                                            const float* __restrict__ Wqkv,
                                            const float* __restrict__ Wo,
                                            const int* __restrict__ pos,
                                            const float* __restrict__ mask,
                                            unsigned short* __restrict__ Xb,
                                            unsigned short* __restrict__ WqkvT,
                                            unsigned short* __restrict__ WoT,
                                            float* __restrict__ ctab,
                                            float* __restrict__ stab,
                                            int* __restrict__ flags) {
  __shared__ float tile[32][33];
  __shared__ int sflag;
  const int b = blockIdx.x;
  const int tid = threadIdx.x;
  if (b < 3072) {
    int i = (b * 256 + tid) * 4;
    float4 v = *(const float4*)(X + i);
    ushort4 o;
    o.x = f2bf(v.x); o.y = f2bf(v.y); o.z = f2bf(v.z); o.w = f2bf(v.w);
    *(ushort4*)(Xb + i) = o;
  } else if (b < 6144) {
    int b2 = b - 3072;
    int c0 = (b2 % 96) * 32, r0 = (b2 / 96) * 32;
    int tx = tid & 31, ty = tid >> 5;
    #pragma unroll
    for (int i2 = 0; i2 < 32; i2 += 8)
      tile[ty + i2][tx] = Wqkv[(size_t)(r0 + ty + i2) * 3072 + c0 + tx];
    __syncthreads();
    #pragma unroll
    for (int i2 = 0; i2 < 32; i2 += 8)
      WqkvT[(size_t)(c0 + ty + i2) * 1024 + r0 + tx] = f2bf(tile[tx][ty + i2]);
  } else if (b < 7168) {
    int b2 = b - 6144;
    int c0 = (b2 % 32) * 32, r0 = (b2 / 32) * 32;
    int tx = tid & 31, ty = tid >> 5;
    #pragma unroll
    for (int i2 = 0; i2 < 32; i2 += 8)
      tile[ty + i2][tx] = Wo[(size_t)(r0 + ty + i2) * 1024 + c0 + tx];
    __syncthreads();
    #pragma unroll
    for (int i2 = 0; i2 < 32; i2 += 8)
      WoT[(size_t)(c0 + ty + i2) * 1024 + r0 + tx] = f2bf(tile[tx][ty + i2]);
  } else if (b < 7552) {
    int i = (b - 7168) * 256 + tid;   // T*32
    int t = i >> 5, j = i & 31;
    float inv = expf(-(float)j * 0.28782313662425572f);  // 10000^(-j/32)
    float f = (float)pos[t] * inv;
    ctab[i] = cosf(f);
    stab[i] = sinf(f);
  } else {
    int c = b - 7552;                 // 96 chunks
    int qx = c % NQB, z = c / NQB;
    const float* base = mask + (size_t)(qx * 128) * T_TOK + z * KVCHUNK;
    int any = 0;
    const int NC4 = KVCHUNK / 4;      // 192
    for (int i = tid; i < 128 * NC4; i += 256) {
      int row = i / NC4, cc = i - row * NC4;
      float4 v = *(const float4*)(base + (size_t)row * T_TOK + cc * 4);
      any |= (v.x != 0.f) | (v.y != 0.f) | (v.z != 0.f) | (v.w != 0.f);
    }
    if (tid == 0) sflag = 0;
    __syncthreads();
    if (__any(any) && (tid & 63) == 0) sflag = 1;  // benign same-value race
    __syncthreads();
    if (tid == 0) flags[z * NQB + qx] = sflag;
  }
}

// ---------------- fused QKV GEMM + RoPE + V-transpose epilogue (R16-proven) ----------------
__global__ __launch_bounds__(256) void gemm_qkv(const unsigned short* __restrict__ A,
                                                const unsigned short* __restrict__ Bt,
                                                const float* __restrict__ ctab,
                                                const float* __restrict__ stab,
                                                unsigned short* __restrict__ Qh,
                                                unsigned short* __restrict__ Kh,
                                                unsigned short* __restrict__ Vt) {
  const int M = T_TOK, N = 3 * HID, K = HID;
  __shared__ unsigned short As[2][128 * 32];
  __shared__ unsigned short Bs[2][128 * 32];
  const int lane = threadIdx.x & 63;
  const int wv = threadIdx.x >> 6;
  const int wm = wv >> 1, wn = wv & 1;
  const int r = lane & 15, hi = lane >> 4;
  const int nwg = gridDim.x;
  const int flat = blockIdx.x;
  const int sid = (flat & 7) * (nwg >> 3) + (flat >> 3);
  const int mblocks = M >> 7;
  const int m0 = (sid % mblocks) * 128, n0 = (sid / mblocks) * 128;

  const int srow = lane >> 2;
  const int scb  = ((lane & 3) * 16) ^ ((srow & 3) << 4);
  const unsigned short* ga = A  + (size_t)(m0 + wv * 16 + srow) * K + (scb >> 1);
  const unsigned short* gb = Bt + (size_t)(n0 + wv * 16 + srow) * K + (scb >> 1);
  char* asd = (char*)&As[0][0] + wv * 1024;
  char* bsd = (char*)&Bs[0][0] + wv * 1024;

  auto stage = [&](int buf, int kt) {
    __builtin_amdgcn_global_load_lds(
        (const __attribute__((address_space(1))) unsigned int*)(ga + kt),
        (__attribute__((address_space(3))) unsigned int*)(asd + buf * 8192), 16, 0, 0);
    __builtin_amdgcn_global_load_lds(
        (const __attribute__((address_space(1))) unsigned int*)(ga + (size_t)64 * K + kt),
        (__attribute__((address_space(3))) unsigned int*)(asd + buf * 8192 + 4096), 16, 0, 0);
    __builtin_amdgcn_global_load_lds(
        (const __attribute__((address_space(1))) unsigned int*)(gb + kt),
        (__attribute__((address_space(3))) unsigned int*)(bsd + buf * 8192), 16, 0, 0);
    __builtin_amdgcn_global_load_lds(
        (const __attribute__((address_space(1))) unsigned int*)(gb + (size_t)64 * K + kt),
        (__attribute__((address_space(3))) unsigned int*)(bsd + buf * 8192 + 4096), 16, 0, 0);
  };

  f32x4 acc[4][4] = {};
  const int NT = K >> 5;
  stage(0, 0);
  #pragma unroll 2
  for (int it = 0; it < NT; ++it) {
    const int buf = it & 1;
    if (it + 1 < NT) {
      stage(buf ^ 1, (it + 1) * 32);
      VMCNT(4);
    } else {
      VMCNT(0);
    }
    SB();
    __builtin_amdgcn_s_barrier();
    SB();
    bf16x8 a[4], b[4];
    const int cbs = (hi * 16) ^ ((r & 3) << 4);
    #pragma unroll
    for (int tm = 0; tm < 4; ++tm)
      a[tm] = *(const bf16x8*)&As[buf][(wm * 64 + tm * 16 + r) * 32 + (cbs >> 1)];
    #pragma unroll
    for (int tn = 0; tn < 4; ++tn)
      b[tn] = *(const bf16x8*)&Bs[buf][(wn * 64 + tn * 16 + r) * 32 + (cbs >> 1)];
    #pragma unroll
    for (int tm = 0; tm < 4; ++tm)
      #pragma unroll
      for (int tn = 0; tn < 4; ++tn)
        acc[tm][tn] = __builtin_amdgcn_mfma_f32_16x16x32_bf16(a[tm], b[tn], acc[tm][tn], 0, 0, 0);
    __builtin_amdgcn_s_barrier();
  }

  const int sec = n0 >> 10;                        // 0=Q, 1=K, 2=V
  const int hh  = ((n0 + wn * 64) >> 6) & 15;      // head (per-wave constant)
  if (sec < 2) {
    __syncthreads();
    float* ctl = (float*)&As[0][0];   // [128][32]
    float* stl = (float*)&Bs[0][0];
    for (int i = threadIdx.x; i < 1024; i += 256) {
      ((float4*)ctl)[i] = *(const float4*)(ctab + (size_t)m0 * 32 + i * 4);
      ((float4*)stl)[i] = *(const float4*)(stab + (size_t)m0 * 32 + i * 4);
    }
    __syncthreads();
    const float qscl = (sec == 0) ? 0.18033688011112042f : 1.0f;  // 0.125*log2e on Q
    unsigned short* dst = (sec == 0) ? Qh : Kh;
    #pragma unroll
    for (int tm = 0; tm < 4; ++tm)
      #pragma unroll
      for (int tn2 = 0; tn2 < 2; ++tn2) {
        const int p = tn2 * 16 + r;                // jh in [0,32)
        #pragma unroll
        for (int j = 0; j < 4; ++j) {
          int trow = wm * 64 + tm * 16 + hi * 4 + j;
          float c = ctl[trow * 32 + p], s = stl[trow * 32 + p];
          float q1 = acc[tm][tn2][j], q2 = acc[tm][tn2 + 2][j];
          size_t base = ((size_t)hh * T_TOK + (m0 + trow)) * HD + p;
          dst[base]      = f2bf((q1 * c - q2 * s) * qscl);
          dst[base + 32] = f2bf((q2 * c + q1 * s) * qscl);
        }
      }
  } else {
    const int hi2 = ((hi & 1) << 1) | (hi >> 1);
    #pragma unroll
    for (int tn = 0; tn < 4; ++tn) {
      const int d = tn * 16 + r;
      #pragma unroll
      for (int tm = 0; tm < 4; ++tm) {
        int tbase = m0 + wm * 64 + tm * 16 + hi2 * 4;
        ushort4 w;
        w.x = f2bf(acc[tm][tn][0]); w.y = f2bf(acc[tm][tn][1]);
        w.z = f2bf(acc[tm][tn][2]); w.w = f2bf(acc[tm][tn][3]);
        *(ushort4*)(Vt + ((size_t)hh * HD + d) * T_TOK + tbase) = w;
      }
    }
  }
}

// ---------------- GEMM: counted-vmcnt double-buffered pipeline (R12-proven) ----------------
__global__ __launch_bounds__(256) void gemm_bt(const unsigned short* __restrict__ A,
                                               const unsigned short* __restrict__ Bt,
                                               float* __restrict__ C, int M, int N, int K) {
  __shared__ unsigned short As[2][128 * 32];
  __shared__ unsigned short Bs[2][128 * 32];
  const int lane = threadIdx.x & 63;
  const int wv = threadIdx.x >> 6;
  const int wm = wv >> 1, wn = wv & 1;
  const int r = lane & 15, hi = lane >> 4;
  const int nwg = gridDim.x;
  const int flat = blockIdx.x;
  const int sid = (flat & 7) * (nwg >> 3) + (flat >> 3);
  const int mblocks = M >> 7;
  const int m0 = (sid % mblocks) * 128, n0 = (sid / mblocks) * 128;

  const int srow = lane >> 2;
  const int scb  = ((lane & 3) * 16) ^ ((srow & 3) << 4);
  const unsigned short* ga = A  + (size_t)(m0 + wv * 16 + srow) * K + (scb >> 1);
  const unsigned short* gb = Bt + (size_t)(n0 + wv * 16 + srow) * K + (scb >> 1);
  char* asd = (char*)&As[0][0] + wv * 1024;
  char* bsd = (char*)&Bs[0][0] + wv * 1024;

  auto stage = [&](int buf, int kt) {
    __builtin_amdgcn_global_load_lds(
        (const __attribute__((address_space(1))) unsigned int*)(ga + kt),
        (__attribute__((address_space(3))) unsigned int*)(asd + buf * 8192), 16, 0, 0);
    __builtin_amdgcn_global_load_lds(
        (const __attribute__((address_space(1))) unsigned int*)(ga + (size_t)64 * K + kt),
        (__attribute__((address_space(3))) unsigned int*)(asd + buf * 8192 + 4096), 16, 0, 0);
    __builtin_amdgcn_global_load_lds(
        (const __attribute__((address_space(1))) unsigned int*)(gb + kt),
        (__attribute__((address_space(3))) unsigned int*)(bsd + buf * 8192), 16, 0, 0);
    __builtin_amdgcn_global_load_lds(
        (const __attribute__((address_space(1))) unsigned int*)(gb + (size_t)64 * K + kt),
        (__attribute__((address_space(3))) unsigned int*)(bsd + buf * 8192 + 4096), 16, 0, 0);
  };

  f32x4 acc[4][4] = {};
  const int NT = K >> 5;
  stage(0, 0);
  #pragma unroll 2
  for (int it = 0; it < NT; ++it) {
    const int buf = it & 1;
    if (it + 1 < NT) {
      stage(buf ^ 1, (it + 1) * 32);
      VMCNT(4);
    } else {
      VMCNT(0);
    }
    SB();
    __builtin_amdgcn_s_barrier();
    SB();
    bf16x8 a[4], b[4];
    const int cbs = (hi * 16) ^ ((r & 3) << 4);
    #pragma unroll
    for (int tm = 0; tm < 4; ++tm)
      a[tm] = *(const bf16x8*)&As[buf][(wm * 64 + tm * 16 + r) * 32 + (cbs >> 1)];
    #pragma unroll
    for (int tn = 0; tn < 4; ++tn)
      b[tn] = *(const bf16x8*)&Bs[buf][(wn * 64 + tn * 16 + r) * 32 + (cbs >> 1)];
    #pragma unroll
    for (int tm = 0; tm < 4; ++tm)
      #pragma unroll
      for (int tn = 0; tn < 4; ++tn)
        acc[tm][tn] = __builtin_amdgcn_mfma_f32_16x16x32_bf16(a[tm], b[tn], acc[tm][tn], 0, 0, 0);
    __builtin_amdgcn_s_barrier();
  }
  #pragma unroll
  for (int tm = 0; tm < 4; ++tm)
    #pragma unroll
    for (int tn = 0; tn < 4; ++tn) {
      int colg = n0 + wn * 64 + tn * 16 + r;
      int rowg = m0 + wm * 64 + tm * 16 + hi * 4;
      float* cp = C + (size_t)rowg * N + colg;
      #pragma unroll
      for (int j = 0; j < 4; ++j) cp[(size_t)j * N] = acc[tm][tn][j];
    }
}

// ---------------- flash attention ----------------
// No-mask path: software-pipelined QK^T -- K staged 2 tiles ahead, V 1 ahead;
// qkt(t+1) [MFMA] overlaps softmax(t) [VALU] (different pipes, independent);
// S-accumulators double-buffered in registers (static names, unroll-by-2).
// Steady-state VMCNT(4) pops exactly {V(t), K(t+1)}. 2 barriers/tile.
// Mask path: R15 online-softmax (unchanged).
__global__ __launch_bounds__(256) void flash_attn(const unsigned short* __restrict__ Qh,
                                                  const unsigned short* __restrict__ Kh,
                                                  const unsigned short* __restrict__ Vt,
                                                  const float* __restrict__ mask,
                                                  const int* __restrict__ flags,
                                                  unsigned short* __restrict__ Op,
                                                  float* __restrict__ Mp,
                                                  float* __restrict__ Lp) {
  const int NBLK = NH * NQB * KVSPLIT;              // 1536
  int id = blockIdx.x;
  int sid = (id & 7) * (NBLK / 8) + (id >> 3);      // XCD gets contiguous sid chunk
  const int hh = sid / (NQB * KVSPLIT);             // h slowest: 2 heads per XCD
  int rem = sid % (NQB * KVSPLIT);
  const int z  = rem / NQB;
  const int qx = rem % NQB;
  const int q0 = qx * 128;
  const int kv0 = z * KVCHUNK;
  const int NT = KVCHUNK / 64;                      // 12 (even)

  __shared__ unsigned short Ks[2][64 * 64];
  __shared__ unsigned short Vs[2][64 * 64];
  const int lane = threadIdx.x & 63, wv = threadIdx.x >> 6;
  const int q31 = lane & 31, h2 = lane >> 5;
  const int qw = q0 + wv * 32 + q31;

  bf16x8 qf[4];
  #pragma unroll
  for (int ks = 0; ks < 4; ++ks)
    qf[ks] = *(const bf16x8*)(Qh + ((size_t)hh * T_TOK + qw) * HD + ks * 16 + h2 * 8);

  f32x16 acc_o[2] = {};
  const int hasmask = flags[z * NQB + qx];
  float m = hasmask ? -INFINITY : 0.f;
  float l = 0.f;

  const int ldrow = lane >> 3;
  const int colS  = ((lane & 7) * 16) ^ (ldrow << 4);
  const unsigned short* kga = Kh + ((size_t)hh * T_TOK + wv * 16 + ldrow) * HD + (colS >> 1);
  const unsigned short* vga = Vt + ((size_t)hh * HD + wv * 16 + ldrow) * T_TOK + (colS >> 1);
  char* ksd = (char*)&Ks[0][0] + wv * 2048;
  char* vsd = (char*)&Vs[0][0] + wv * 2048;
  const float* mrow = mask + (size_t)qw * T_TOK;

  auto stageK = [&](int buf, int s0) {
    __builtin_amdgcn_global_load_lds(
        (const __attribute__((address_space(1))) unsigned int*)(kga + (size_t)s0 * HD),
        (__attribute__((address_space(3))) unsigned int*)(ksd + buf * 8192), 16, 0, 0);
    __builtin_amdgcn_global_load_lds(
        (const __attribute__((address_space(1))) unsigned int*)(kga + (size_t)s0 * HD + 8 * HD),
        (__attribute__((address_space(3))) unsigned int*)(ksd + buf * 8192 + 1024), 16, 0, 0);
  };
  auto stageV = [&](int buf, int s0) {
    __builtin_amdgcn_global_load_lds(
        (const __attribute__((address_space(1))) unsigned int*)(vga + s0),
        (__attribute__((address_space(3))) unsigned int*)(vsd + buf * 8192), 16, 0, 0);
    __builtin_amdgcn_global_load_lds(
        (const __attribute__((address_space(1))) unsigned int*)(vga + s0 + 8 * T_TOK),
        (__attribute__((address_space(3))) unsigned int*)(vsd + buf * 8192 + 1024), 16, 0, 0);
  };

  auto qkt = [&](int cur, f32x16& as0, f32x16& as1) {
    __builtin_amdgcn_s_setprio(1);
    #pragma unroll
    for (int ks = 0; ks < 4; ++ks) {
      bf16x8 kf0 = *(const bf16x8*)&Ks[cur][swz(q31,      ks * 32 + h2 * 16)];
      bf16x8 kf1 = *(const bf16x8*)&Ks[cur][swz(32 + q31, ks * 32 + h2 * 16)];
      as0 = __builtin_amdgcn_mfma_f32_32x32x16_bf16(kf0, qf[ks], as0, 0, 0, 0);
      as1 = __builtin_amdgcn_mfma_f32_32x32x16_bf16(kf1, qf[ks], as1, 0, 0, 0);
    }
    __builtin_amdgcn_s_setprio(0);
  };

  auto pv = [&](int cur, const unsigned int* pk) {
    __builtin_amdgcn_s_setprio(1);
    #pragma unroll
    for (int kvb = 0; kvb < 2; ++kvb)
      #pragma unroll
      for (int s = 0; s < 2; ++s) {
        u32x4 fr;
        fr[0] = pk[kvb * 8 + 4 * s + 0];
        fr[1] = pk[kvb * 8 + 4 * s + 1];
        fr[2] = pk[kvb * 8 + 4 * s + 2];
        fr[3] = pk[kvb * 8 + 4 * s + 3];
        bf16x8 pfrag = __builtin_bit_cast(bf16x8, fr);
        #pragma unroll
        for (int db = 0; db < 2; ++db) {
          bf16x8 vf = *(const bf16x8*)&Vs[cur][swz(db * 32 + q31, kvb * 64 + s * 32 + h2 * 16)];
          acc_o[db] = __builtin_amdgcn_mfma_f32_32x32x16_bf16(vf, pfrag, acc_o[db], 0, 0, 0);
        }
      }
    __builtin_amdgcn_s_setprio(0);
  };

  // softmax from S-regs (fixed base 0), produce pk + update l
  auto softmax0 = [&](const f32x16& as0, const f32x16& as1, unsigned int* pk) {
    float ps = 0.f;
    #pragma unroll
    for (int kvb = 0; kvb < 2; ++kvb) {
      const f32x16& as = kvb ? as1 : as0;
      #pragma unroll
      for (int j = 0; j < 4; ++j) {
        float e0 = __builtin_amdgcn_exp2f(as[j * 4 + 0]);
        float e1 = __builtin_amdgcn_exp2f(as[j * 4 + 1]);
        float e2 = __builtin_amdgcn_exp2f(as[j * 4 + 2]);
        float e3 = __builtin_amdgcn_exp2f(as[j * 4 + 3]);
        ps += (e0 + e1) + (e2 + e3);
        pk[kvb * 8 + j * 2 + 0] = pack_bf16(e0, e1);
        pk[kvb * 8 + j * 2 + 1] = pack_bf16(e2, e3);
      }
    }
    l += ps;
  };

  if (!hasmask) {
    // ---- pipelined no-mask path ----
    f32x16 aA0 = {}, aA1 = {}, aB0 = {}, aB1 = {};
    stageK(0, kv0); stageV(0, kv0);           // queue: K0,V0
    stageK(1, kv0 + 64);                      // queue: K0,V0,K1 (6)
    VMCNT(4);                                 // K0 landed
    SB(); __builtin_amdgcn_s_barrier(); SB();
    qkt(0, aA0, aA1);                         // S(0)
    __builtin_amdgcn_s_barrier();             // all waves done reading Ks[0] as tile 0

    unsigned int pk[16];
    for (int it = 0; it < NT; it += 2) {
      // even sub-iter: consume A(S(it)), build B = S(it+1)
      {
        if (it + 1 < NT) stageV((it + 1) & 1, kv0 + (it + 1) * 64);
        if (it + 2 < NT) stageK(it & 1,       kv0 + (it + 2) * 64);
        if (it + 2 < NT)      { VMCNT(4); }   // pop {V(it), K(it+1)}
        else if (it + 1 < NT) { VMCNT(2); }
        else                  { VMCNT(0); }
        SB(); __builtin_amdgcn_s_barrier(); SB();
        if (it + 1 < NT) {
          aB0 = (f32x16){}; aB1 = (f32x16){};
          qkt((it + 1) & 1, aB0, aB1);        // MFMA, overlaps softmax below
        }
        softmax0(aA0, aA1, pk);               // VALU
        pv(it & 1, pk);
        __builtin_amdgcn_s_barrier();
      }
      // odd sub-iter: consume B(S(it+1)), build A = S(it+2)
      if (it + 1 < NT) {
        const int jt = it + 1;
        if (jt + 1 < NT) stageV((jt + 1) & 1, kv0 + (jt + 1) * 64);
        if (jt + 2 < NT) stageK(jt & 1,       kv0 + (jt + 2) * 64);
        if (jt + 2 < NT)      { VMCNT(4); }
        else if (jt + 1 < NT) { VMCNT(2); }
        else                  { VMCNT(0); }
        SB(); __builtin_amdgcn_s_barrier(); SB();
        if (jt + 1 < NT) {
          aA0 = (f32x16){}; aA1 = (f32x16){};
          qkt((jt + 1) & 1, aA0, aA1);
        }
        softmax0(aB0, aB1, pk);
        pv(jt & 1, pk);
        __builtin_amdgcn_s_barrier();
      }
    }
  } else {
    // ---- mask path (R15 structure, unchanged) ----
    auto stage = [&](int buf, int s0) {
      stageK(buf, s0);
      stageV(buf, s0);
    };
    float4 mk[8];
    auto tile_mask = [&](int cur) {
      f32x16 as0 = {}, as1 = {};
      qkt(cur, as0, as1);
      float sv[2][16];
      #pragma unroll
      for (int reg = 0; reg < 16; ++reg) {
        float m0v = (&mk[0 + (reg >> 2)].x)[reg & 3];
        float m1v = (&mk[4 + (reg >> 2)].x)[reg & 3];
        sv[0][reg] = fmaf(m0v, LOG2E, as0[reg]);
        sv[1][reg] = fmaf(m1v, LOG2E, as1[reg]);
      }
      float p0 = sv[0][0];
      #pragma unroll
      for (int i = 1; i < 16; ++i) p0 = fmaxf(p0, sv[0][i]);
      #pragma unroll
      for (int i = 0; i < 16; ++i) p0 = fmaxf(p0, sv[1][i]);
      float pmax = fmaxf(p0, __shfl_xor(p0, 32));
      if (__any(pmax > m + 8.f)) {
        float mnew = fmaxf(m, pmax);
        float sc = __builtin_amdgcn_exp2f(m - mnew);
        m = mnew;
        l *= sc;
        #pragma unroll
        for (int db = 0; db < 2; ++db)
          #pragma unroll
          for (int i = 0; i < 16; ++i) acc_o[db][i] *= sc;
      }
      float ps = 0.f;
      unsigned int pk[16];
      #pragma unroll
      for (int kvb = 0; kvb < 2; ++kvb)
        #pragma unroll
        for (int j = 0; j < 4; ++j) {
          float e0 = __builtin_amdgcn_exp2f(sv[kvb][j * 4 + 0] - m);
          float e1 = __builtin_amdgcn_exp2f(sv[kvb][j * 4 + 1] - m);
          float e2 = __builtin_amdgcn_exp2f(sv[kvb][j * 4 + 2] - m);
          float e3 = __builtin_amdgcn_exp2f(sv[kvb][j * 4 + 3] - m);
          ps += (e0 + e1) + (e2 + e3);
          pk[kvb * 8 + j * 2 + 0] = pack_bf16(e0, e1);
          pk[kvb * 8 + j * 2 + 1] = pack_bf16(e2, e3);
        }
      l += ps;
      pv(cur, pk);
    };

    stage(0, kv0);
    for (int it = 0; it < NT - 1; ++it) {
      const int s0 = kv0 + it * 64;
      #pragma unroll
      for (int kvb = 0; kvb < 2; ++kvb)
        #pragma unroll
        for (int g = 0; g < 4; ++g)
          mk[kvb * 4 + g] = *(const float4*)(mrow + s0 + kvb * 32 + g * 8 + 4 * h2);
      stage((it + 1) & 1, s0 + 64);
      VMCNT(12);
      SB();
      __builtin_amdgcn_s_barrier();
      SB();
      tile_mask(it & 1);
      __builtin_amdgcn_s_barrier();
    }
    const int s0 = kv0 + (NT - 1) * 64;
    #pragma unroll
    for (int kvb = 0; kvb < 2; ++kvb)
      #pragma unroll
      for (int g = 0; g < 4; ++g)
        mk[kvb * 4 + g] = *(const float4*)(mrow + s0 + kvb * 32 + g * 8 + 4 * h2);
    VMCNT(8);
    SB();
    __builtin_amdgcn_s_barrier();
    SB();
    tile_mask((NT - 1) & 1);
  }

  // epilogue: normalize by 1/l, store f16 partials
  float lf = l + __shfl_xor(l, 32);
  float lfinv = 1.f / lf;
  unsigned short* oprow = Op + (((size_t)z * T_TOK + qw) * NH + hh) * HD;
  #pragma unroll
  for (int db = 0; db < 2; ++db)
    #pragma unroll
    for (int g = 0; g < 4; ++g) {
      ushort4 o4;
      o4.x = f2h(acc_o[db][g * 4 + 0] * lfinv);
      o4.y = f2h(acc_o[db][g * 4 + 1] * lfinv);
      o4.z = f2h(acc_o[db][g * 4 + 2] * lfinv);
      o4.w = f2h(acc_o[db][g * 4 + 3] * lfinv);
      *(ushort4*)(oprow + db * 32 + g * 8 + 4 * h2) = o4;
    }
  if (h2 == 0) {
    size_t mi = ((size_t)z * T_TOK + qw) * NH + hh;
    Mp[mi] = m;
    Lp[mi] = lf;
  }
}

// ---------------- combine KV-split partials (normalized f16 Op) ----------------
__global__ __launch_bounds__(256) void combine(const unsigned short* __restrict__ Op,
                                               const float* __restrict__ Mp,
                                               const float* __restrict__ Lp,
                                               unsigned short* __restrict__ Ob) {
  int idx = blockIdx.x * 256 + threadIdx.x;
  int t = idx >> 8;
  int q4 = (idx & 255) * 4;
  int h = q4 >> 6, d = q4 & 63;
  float mz[KVSPLIT], lz[KVSPLIT];
  float ms = -INFINITY;
  #pragma unroll
  for (int zz = 0; zz < KVSPLIT; ++zz) {
    size_t mi = ((size_t)zz * T_TOK + t) * NH + h;
    mz[zz] = Mp[mi];
    lz[zz] = Lp[mi];
    ms = fmaxf(ms, mz[zz]);
  }
  float lsum = 0.f;
  float wl[KVSPLIT];
  #pragma unroll
  for (int zz = 0; zz < KVSPLIT; ++zz) {
    wl[zz] = lz[zz] * __builtin_amdgcn_exp2f(mz[zz] - ms);
    lsum += wl[zz];
  }
  float4 o = {0.f, 0.f, 0.f, 0.f};
  #pragma unroll
  for (int zz = 0; zz < KVSPLIT; ++zz) {
    ushort4 p = *(const ushort4*)(Op + (((size_t)zz * T_TOK + t) * NH + h) * HD + d);
    o.x += h2f(p.x) * wl[zz]; o.y += h2f(p.y) * wl[zz];
    o.z += h2f(p.z) * wl[zz]; o.w += h2f(p.w) * wl[zz];
  }
  float inv = 1.f / lsum;
  ushort4 ob;
  ob.x = f2bf(o.x * inv); ob.y = f2bf(o.y * inv);
  ob.z = f2bf(o.z * inv); ob.w = f2bf(o.w * inv);
  *(ushort4*)(Ob + (size_t)t * HID + q4) = ob;
}

extern "C" void kernel_launch(void* const* d_in, const int* in_sizes, int n_in,
                              void* d_out, int out_size, void* d_ws, size_t ws_size,
                              hipStream_t stream) {
  const float* X    = (const float*)d_in[0];
  const float* Wqkv = (const float*)d_in[1];
  const float* Wo   = (const float*)d_in[2];
  const float* mask = (const float*)d_in[3];
  const int*   pos  = (const int*)d_in[4];
  float* out = (float*)d_out;

  char* ws = (char*)d_ws;
  size_t off = 0;
  auto alloc = [&](size_t bytes) {
    char* p = ws + off;
    off += (bytes + 255) & ~(size_t)255;
    return p;
  };
  unsigned short* Xb    = (unsigned short*)alloc((size_t)T_TOK * HID * 2);
  unsigned short* WqkvT = (unsigned short*)alloc((size_t)3 * HID * HID * 2);
  unsigned short* WoT   = (unsigned short*)alloc((size_t)HID * HID * 2);
  unsigned short* Qh    = (unsigned short*)alloc((size_t)NH * T_TOK * HD * 2);
  unsigned short* Kh    = (unsigned short*)alloc((size_t)NH * T_TOK * HD * 2);
  unsigned short* Vt    = (unsigned short*)alloc((size_t)NH * HD * T_TOK * 2);
  unsigned short* Ob    = (unsigned short*)alloc((size_t)T_TOK * HID * 2);
  float*          ctab  = (float*)alloc((size_t)T_TOK * 32 * 4);
  float*          stab  = (float*)alloc((size_t)T_TOK * 32 * 4);
  float*          Mp    = (float*)alloc((size_t)KVSPLIT * T_TOK * NH * 4);
  float*          Lp    = (float*)alloc((size_t)KVSPLIT * T_TOK * NH * 4);
  int*            flags = (int*)alloc((size_t)KVSPLIT * NQB * 4);
  unsigned short* Op    = (unsigned short*)alloc((size_t)KVSPLIT * T_TOK * HID * 2);

  prep<<<7648, 256, 0, stream>>>(X, Wqkv, Wo, pos, mask, Xb, WqkvT, WoT, ctab, stab, flags);

  gemm_qkv<<<dim3((3 * HID / 128) * (T_TOK / 128)), 256, 0, stream>>>(Xb, WqkvT, ctab, stab, Qh, Kh, Vt);

  flash_attn<<<dim3(NH * NQB * KVSPLIT), 256, 0, stream>>>(Qh, Kh, Vt, mask, flags, Op, Mp, Lp);
  combine<<<T_TOK, 256, 0, stream>>>(Op, Mp, Lp, Ob);

  gemm_bt<<<dim3((HID / 128) * (T_TOK / 128)), 256, 0, stream>>>(Ob, WoT, out, T_TOK, HID, HID);
}

// Round 19
// 140.445 us; speedup vs baseline: 1.3864x; 1.0571x over previous
//
#include <hip/hip_runtime.h>
#include <hip/hip_bf16.h>
#include <hip/hip_fp16.h>
#include <math.h>

#define T_TOK 3072
#define HID   1024
#define NH    16
#define HD    64
#define KVSPLIT 4
#define KVCHUNK (T_TOK / KVSPLIT)   // 768
#define NQB (T_TOK / 128)           // 24 q-tiles of 128 rows
#define LOG2E 1.4426950408889634f

typedef __attribute__((ext_vector_type(8))) short bf16x8;
typedef __attribute__((ext_vector_type(8))) unsigned short u16x8;
typedef __attribute__((ext_vector_type(4))) float f32x4;
typedef __attribute__((ext_vector_type(16))) float f32x16;
typedef __attribute__((ext_vector_type(4))) unsigned int u32x4;

#define VMCNT(n) asm volatile("s_waitcnt vmcnt(" #n ")" ::: "memory")
#define SB() __builtin_amdgcn_sched_barrier(0)

static __device__ __forceinline__ unsigned short f2bf(float x) {
  __hip_bfloat16 h = __float2bfloat16(x);
  return __builtin_bit_cast(unsigned short, h);
}
static __device__ __forceinline__ float bf2f(unsigned short u) {
  unsigned int v = (unsigned int)u << 16;
  return __builtin_bit_cast(float, v);
}
static __device__ __forceinline__ unsigned short f2h(float x) {
  __half h = __float2half(x);
  return __builtin_bit_cast(unsigned short, h);
}
static __device__ __forceinline__ float h2f(unsigned short u) {
  __half h = __builtin_bit_cast(__half, u);
  return __half2float(h);
}
// fast bf16 pair pack, round-half-up (P >= 0, never NaN): ~4 VALU per pair
static __device__ __forceinline__ unsigned int pack_bf16(float a, float b) {
  unsigned int ua = __builtin_bit_cast(unsigned int, a) + 0x8000u;
  unsigned int ub = __builtin_bit_cast(unsigned int, b) + 0x8000u;
  return (ua >> 16) | (ub & 0xffff0000u);
}

// swizzled LDS short-index for a [rows][64 bf16] tile, row stride 128B (flash).
static __device__ __forceinline__ int swz(int row, int cb) {
  return row * 64 + ((cb ^ ((row & 7) << 4)) >> 1);
}

// ---------------- merged preprocessing (block-range dispatch) ----------------
// Mask scan parallelized: 8 sub-blocks per (qx,z) chunk publish via atomicOr
// (flags pre-zeroed by hipMemsetAsync) -> mask read runs at ~full HBM BW.
__global__ __launch_bounds__(256) void prep(const float* __restrict__ X,
                                            const float* __restrict__ Wqkv,
                                            const float* __restrict__ Wo,
                                            const int* __restrict__ pos,
                                            const float* __restrict__ mask,
                                            unsigned short* __restrict__ Xb,
                                            unsigned short* __restrict__ WqkvT,
                                            unsigned short* __restrict__ WoT,
                                            float* __restrict__ ctab,
                                            float* __restrict__ stab,
                                            int* __restrict__ flags) {
  __shared__ float tile[32][33];
  const int b = blockIdx.x;
  const int tid = threadIdx.x;
  if (b < 3072) {
    int i = (b * 256 + tid) * 4;
    float4 v = *(const float4*)(X + i);
    ushort4 o;
    o.x = f2bf(v.x); o.y = f2bf(v.y); o.z = f2bf(v.z); o.w = f2bf(v.w);
    *(ushort4*)(Xb + i) = o;
  } else if (b < 6144) {
    int b2 = b - 3072;
    int c0 = (b2 % 96) * 32, r0 = (b2 / 96) * 32;
    int tx = tid & 31, ty = tid >> 5;
    #pragma unroll
    for (int i2 = 0; i2 < 32; i2 += 8)
      tile[ty + i2][tx] = Wqkv[(size_t)(r0 + ty + i2) * 3072 + c0 + tx];
    __syncthreads();
    #pragma unroll
    for (int i2 = 0; i2 < 32; i2 += 8)
      WqkvT[(size_t)(c0 + ty + i2) * 1024 + r0 + tx] = f2bf(tile[tx][ty + i2]);
  } else if (b < 7168) {
    int b2 = b - 6144;
    int c0 = (b2 % 32) * 32, r0 = (b2 / 32) * 32;
    int tx = tid & 31, ty = tid >> 5;
    #pragma unroll
    for (int i2 = 0; i2 < 32; i2 += 8)
      tile[ty + i2][tx] = Wo[(size_t)(r0 + ty + i2) * 1024 + c0 + tx];
    __syncthreads();
    #pragma unroll
    for (int i2 = 0; i2 < 32; i2 += 8)
      WoT[(size_t)(c0 + ty + i2) * 1024 + r0 + tx] = f2bf(tile[tx][ty + i2]);
  } else if (b < 7552) {
    int i = (b - 7168) * 256 + tid;   // T*32
    int t = i >> 5, j = i & 31;
    float inv = expf(-(float)j * 0.28782313662425572f);  // 10000^(-j/32)
    float f = (float)pos[t] * inv;
    ctab[i] = cosf(f);
    stab[i] = sinf(f);
  } else {
    // mask nonzero scan: 768 blocks = 96 chunks x 8 sub-blocks of 16 rows each
    int c = b - 7552;
    int chunk = c >> 3, sub = c & 7;
    int qx = chunk % NQB, z = chunk / NQB;
    const float* base = mask + (size_t)(qx * 128 + sub * 16) * T_TOK + z * KVCHUNK;
    int any = 0;
    const int NC4 = KVCHUNK / 4;      // 192
    for (int i = tid; i < 16 * NC4; i += 256) {
      int row = i / NC4, cc = i - row * NC4;
      float4 v = *(const float4*)(base + (size_t)row * T_TOK + cc * 4);
      any |= (v.x != 0.f) | (v.y != 0.f) | (v.z != 0.f) | (v.w != 0.f);
    }
    if (__any(any) && (tid & 63) == 0)
      atomicOr(&flags[z * NQB + qx], 1);
  }
}

// ---------------- fused QKV GEMM + RoPE + V-transpose epilogue (R16-proven) ----------------
__global__ __launch_bounds__(256) void gemm_qkv(const unsigned short* __restrict__ A,
                                                const unsigned short* __restrict__ Bt,
                                                const float* __restrict__ ctab,
                                                const float* __restrict__ stab,
                                                unsigned short* __restrict__ Qh,
                                                unsigned short* __restrict__ Kh,
                                                unsigned short* __restrict__ Vt) {
  const int M = T_TOK, N = 3 * HID, K = HID;
  __shared__ unsigned short As[2][128 * 32];
  __shared__ unsigned short Bs[2][128 * 32];
  const int lane = threadIdx.x & 63;
  const int wv = threadIdx.x >> 6;
  const int wm = wv >> 1, wn = wv & 1;
  const int r = lane & 15, hi = lane >> 4;
  const int nwg = gridDim.x;
  const int flat = blockIdx.x;
  const int sid = (flat & 7) * (nwg >> 3) + (flat >> 3);
  const int mblocks = M >> 7;
  const int m0 = (sid % mblocks) * 128, n0 = (sid / mblocks) * 128;

  const int srow = lane >> 2;
  const int scb  = ((lane & 3) * 16) ^ ((srow & 3) << 4);
  const unsigned short* ga = A  + (size_t)(m0 + wv * 16 + srow) * K + (scb >> 1);
  const unsigned short* gb = Bt + (size_t)(n0 + wv * 16 + srow) * K + (scb >> 1);
  char* asd = (char*)&As[0][0] + wv * 1024;
  char* bsd = (char*)&Bs[0][0] + wv * 1024;

  auto stage = [&](int buf, int kt) {
    __builtin_amdgcn_global_load_lds(
        (const __attribute__((address_space(1))) unsigned int*)(ga + kt),
        (__attribute__((address_space(3))) unsigned int*)(asd + buf * 8192), 16, 0, 0);
    __builtin_amdgcn_global_load_lds(
        (const __attribute__((address_space(1))) unsigned int*)(ga + (size_t)64 * K + kt),
        (__attribute__((address_space(3))) unsigned int*)(asd + buf * 8192 + 4096), 16, 0, 0);
    __builtin_amdgcn_global_load_lds(
        (const __attribute__((address_space(1))) unsigned int*)(gb + kt),
        (__attribute__((address_space(3))) unsigned int*)(bsd + buf * 8192), 16, 0, 0);
    __builtin_amdgcn_global_load_lds(
        (const __attribute__((address_space(1))) unsigned int*)(gb + (size_t)64 * K + kt),
        (__attribute__((address_space(3))) unsigned int*)(bsd + buf * 8192 + 4096), 16, 0, 0);
  };

  f32x4 acc[4][4] = {};
  const int NT = K >> 5;
  stage(0, 0);
  #pragma unroll 2
  for (int it = 0; it < NT; ++it) {
    const int buf = it & 1;
    if (it + 1 < NT) {
      stage(buf ^ 1, (it + 1) * 32);
      VMCNT(4);
    } else {
      VMCNT(0);
    }
    SB();
    __builtin_amdgcn_s_barrier();
    SB();
    bf16x8 a[4], b[4];
    const int cbs = (hi * 16) ^ ((r & 3) << 4);
    #pragma unroll
    for (int tm = 0; tm < 4; ++tm)
      a[tm] = *(const bf16x8*)&As[buf][(wm * 64 + tm * 16 + r) * 32 + (cbs >> 1)];
    #pragma unroll
    for (int tn = 0; tn < 4; ++tn)
      b[tn] = *(const bf16x8*)&Bs[buf][(wn * 64 + tn * 16 + r) * 32 + (cbs >> 1)];
    #pragma unroll
    for (int tm = 0; tm < 4; ++tm)
      #pragma unroll
      for (int tn = 0; tn < 4; ++tn)
        acc[tm][tn] = __builtin_amdgcn_mfma_f32_16x16x32_bf16(a[tm], b[tn], acc[tm][tn], 0, 0, 0);
    __builtin_amdgcn_s_barrier();
  }

  const int sec = n0 >> 10;                        // 0=Q, 1=K, 2=V
  const int hh  = ((n0 + wn * 64) >> 6) & 15;      // head (per-wave constant)
  if (sec < 2) {
    __syncthreads();
    float* ctl = (float*)&As[0][0];   // [128][32]
    float* stl = (float*)&Bs[0][0];
    for (int i = threadIdx.x; i < 1024; i += 256) {
      ((float4*)ctl)[i] = *(const float4*)(ctab + (size_t)m0 * 32 + i * 4);
      ((float4*)stl)[i] = *(const float4*)(stab + (size_t)m0 * 32 + i * 4);
    }
    __syncthreads();
    const float qscl = (sec == 0) ? 0.18033688011112042f : 1.0f;  // 0.125*log2e on Q
    unsigned short* dst = (sec == 0) ? Qh : Kh;
    #pragma unroll
    for (int tm = 0; tm < 4; ++tm)
      #pragma unroll
      for (int tn2 = 0; tn2 < 2; ++tn2) {
        const int p = tn2 * 16 + r;                // jh in [0,32)
        #pragma unroll
        for (int j = 0; j < 4; ++j) {
          int trow = wm * 64 + tm * 16 + hi * 4 + j;
          float c = ctl[trow * 32 + p], s = stl[trow * 32 + p];
          float q1 = acc[tm][tn2][j], q2 = acc[tm][tn2 + 2][j];
          size_t base = ((size_t)hh * T_TOK + (m0 + trow)) * HD + p;
          dst[base]      = f2bf((q1 * c - q2 * s) * qscl);
          dst[base + 32] = f2bf((q2 * c + q1 * s) * qscl);
        }
      }
  } else {
    const int hi2 = ((hi & 1) << 1) | (hi >> 1);
    #pragma unroll
    for (int tn = 0; tn < 4; ++tn) {
      const int d = tn * 16 + r;
      #pragma unroll
      for (int tm = 0; tm < 4; ++tm) {
        int tbase = m0 + wm * 64 + tm * 16 + hi2 * 4;
        ushort4 w;
        w.x = f2bf(acc[tm][tn][0]); w.y = f2bf(acc[tm][tn][1]);
        w.z = f2bf(acc[tm][tn][2]); w.w = f2bf(acc[tm][tn][3]);
        *(ushort4*)(Vt + ((size_t)hh * HD + d) * T_TOK + tbase) = w;
      }
    }
  }
}

// ---------------- GEMM: counted-vmcnt double-buffered pipeline (R12-proven) ----------------
__global__ __launch_bounds__(256) void gemm_bt(const unsigned short* __restrict__ A,
                                               const unsigned short* __restrict__ Bt,
                                               float* __restrict__ C, int M, int N, int K) {
  __shared__ unsigned short As[2][128 * 32];
  __shared__ unsigned short Bs[2][128 * 32];
  const int lane = threadIdx.x & 63;
  const int wv = threadIdx.x >> 6;
  const int wm = wv >> 1, wn = wv & 1;
  const int r = lane & 15, hi = lane >> 4;
  const int nwg = gridDim.x;
  const int flat = blockIdx.x;
  const int sid = (flat & 7) * (nwg >> 3) + (flat >> 3);
  const int mblocks = M >> 7;
  const int m0 = (sid % mblocks) * 128, n0 = (sid / mblocks) * 128;

  const int srow = lane >> 2;
  const int scb  = ((lane & 3) * 16) ^ ((srow & 3) << 4);
  const unsigned short* ga = A  + (size_t)(m0 + wv * 16 + srow) * K + (scb >> 1);
  const unsigned short* gb = Bt + (size_t)(n0 + wv * 16 + srow) * K + (scb >> 1);
  char* asd = (char*)&As[0][0] + wv * 1024;
  char* bsd = (char*)&Bs[0][0] + wv * 1024;

  auto stage = [&](int buf, int kt) {
    __builtin_amdgcn_global_load_lds(
        (const __attribute__((address_space(1))) unsigned int*)(ga + kt),
        (__attribute__((address_space(3))) unsigned int*)(asd + buf * 8192), 16, 0, 0);
    __builtin_amdgcn_global_load_lds(
        (const __attribute__((address_space(1))) unsigned int*)(ga + (size_t)64 * K + kt),
        (__attribute__((address_space(3))) unsigned int*)(asd + buf * 8192 + 4096), 16, 0, 0);
    __builtin_amdgcn_global_load_lds(
        (const __attribute__((address_space(1))) unsigned int*)(gb + kt),
        (__attribute__((address_space(3))) unsigned int*)(bsd + buf * 8192), 16, 0, 0);
    __builtin_amdgcn_global_load_lds(
        (const __attribute__((address_space(1))) unsigned int*)(gb + (size_t)64 * K + kt),
        (__attribute__((address_space(3))) unsigned int*)(bsd + buf * 8192 + 4096), 16, 0, 0);
  };

  f32x4 acc[4][4] = {};
  const int NT = K >> 5;
  stage(0, 0);
  #pragma unroll 2
  for (int it = 0; it < NT; ++it) {
    const int buf = it & 1;
    if (it + 1 < NT) {
      stage(buf ^ 1, (it + 1) * 32);
      VMCNT(4);
    } else {
      VMCNT(0);
    }
    SB();
    __builtin_amdgcn_s_barrier();
    SB();
    bf16x8 a[4], b[4];
    const int cbs = (hi * 16) ^ ((r & 3) << 4);
    #pragma unroll
    for (int tm = 0; tm < 4; ++tm)
      a[tm] = *(const bf16x8*)&As[buf][(wm * 64 + tm * 16 + r) * 32 + (cbs >> 1)];
    #pragma unroll
    for (int tn = 0; tn < 4; ++tn)
      b[tn] = *(const bf16x8*)&Bs[buf][(wn * 64 + tn * 16 + r) * 32 + (cbs >> 1)];
    #pragma unroll
    for (int tm = 0; tm < 4; ++tm)
      #pragma unroll
      for (int tn = 0; tn < 4; ++tn)
        acc[tm][tn] = __builtin_amdgcn_mfma_f32_16x16x32_bf16(a[tm], b[tn], acc[tm][tn], 0, 0, 0);
    __builtin_amdgcn_s_barrier();
  }
  #pragma unroll
  for (int tm = 0; tm < 4; ++tm)
    #pragma unroll
    for (int tn = 0; tn < 4; ++tn) {
      int colg = n0 + wn * 64 + tn * 16 + r;
      int rowg = m0 + wm * 64 + tm * 16 + hi * 4;
      float* cp = C + (size_t)rowg * N + colg;
      #pragma unroll
      for (int j = 0; j < 4; ++j) cp[(size_t)j * N] = acc[tm][tn][j];
    }
}

// ---------------- flash attention (R17 structure, unchanged) ----------------
__global__ __launch_bounds__(256) void flash_attn(const unsigned short* __restrict__ Qh,
                                                  const unsigned short* __restrict__ Kh,
                                                  const unsigned short* __restrict__ Vt,
                                                  const float* __restrict__ mask,
                                                  const int* __restrict__ flags,
                                                  unsigned short* __restrict__ Op,
                                                  float* __restrict__ Mp,
                                                  float* __restrict__ Lp) {
  const int NBLK = NH * NQB * KVSPLIT;              // 1536
  int id = blockIdx.x;
  int sid = (id & 7) * (NBLK / 8) + (id >> 3);      // XCD gets contiguous sid chunk
  const int hh = sid / (NQB * KVSPLIT);             // h slowest: 2 heads per XCD
  int rem = sid % (NQB * KVSPLIT);
  const int z  = rem / NQB;
  const int qx = rem % NQB;
  const int q0 = qx * 128;
  const int kv0 = z * KVCHUNK;
  const int NT = KVCHUNK / 64;                      // 12 (even)

  __shared__ unsigned short Ks[2][64 * 64];
  __shared__ unsigned short Vs[2][64 * 64];
  const int lane = threadIdx.x & 63, wv = threadIdx.x >> 6;
  const int q31 = lane & 31, h2 = lane >> 5;
  const int qw = q0 + wv * 32 + q31;

  bf16x8 qf[4];
  #pragma unroll
  for (int ks = 0; ks < 4; ++ks)
    qf[ks] = *(const bf16x8*)(Qh + ((size_t)hh * T_TOK + qw) * HD + ks * 16 + h2 * 8);

  f32x16 acc_o[2] = {};
  const int hasmask = flags[z * NQB + qx];
  float m = hasmask ? -INFINITY : 0.f;
  float l = 0.f;

  const int ldrow = lane >> 3;
  const int colS  = ((lane & 7) * 16) ^ (ldrow << 4);
  const unsigned short* kga = Kh + ((size_t)hh * T_TOK + wv * 16 + ldrow) * HD + (colS >> 1);
  const unsigned short* vga = Vt + ((size_t)hh * HD + wv * 16 + ldrow) * T_TOK + (colS >> 1);
  char* ksd = (char*)&Ks[0][0] + wv * 2048;
  char* vsd = (char*)&Vs[0][0] + wv * 2048;
  const float* mrow = mask + (size_t)qw * T_TOK;

  auto stageK = [&](int buf, int s0) {
    __builtin_amdgcn_global_load_lds(
        (const __attribute__((address_space(1))) unsigned int*)(kga + (size_t)s0 * HD),
        (__attribute__((address_space(3))) unsigned int*)(ksd + buf * 8192), 16, 0, 0);
    __builtin_amdgcn_global_load_lds(
        (const __attribute__((address_space(1))) unsigned int*)(kga + (size_t)s0 * HD + 8 * HD),
        (__attribute__((address_space(3))) unsigned int*)(ksd + buf * 8192 + 1024), 16, 0, 0);
  };
  auto stageV = [&](int buf, int s0) {
    __builtin_amdgcn_global_load_lds(
        (const __attribute__((address_space(1))) unsigned int*)(vga + s0),
        (__attribute__((address_space(3))) unsigned int*)(vsd + buf * 8192), 16, 0, 0);
    __builtin_amdgcn_global_load_lds(
        (const __attribute__((address_space(1))) unsigned int*)(vga + s0 + 8 * T_TOK),
        (__attribute__((address_space(3))) unsigned int*)(vsd + buf * 8192 + 1024), 16, 0, 0);
  };

  auto qkt = [&](int cur, f32x16& as0, f32x16& as1) {
    __builtin_amdgcn_s_setprio(1);
    #pragma unroll
    for (int ks = 0; ks < 4; ++ks) {
      bf16x8 kf0 = *(const bf16x8*)&Ks[cur][swz(q31,      ks * 32 + h2 * 16)];
      bf16x8 kf1 = *(const bf16x8*)&Ks[cur][swz(32 + q31, ks * 32 + h2 * 16)];
      as0 = __builtin_amdgcn_mfma_f32_32x32x16_bf16(kf0, qf[ks], as0, 0, 0, 0);
      as1 = __builtin_amdgcn_mfma_f32_32x32x16_bf16(kf1, qf[ks], as1, 0, 0, 0);
    }
    __builtin_amdgcn_s_setprio(0);
  };

  auto pv = [&](int cur, const unsigned int* pk) {
    __builtin_amdgcn_s_setprio(1);
    #pragma unroll
    for (int kvb = 0; kvb < 2; ++kvb)
      #pragma unroll
      for (int s = 0; s < 2; ++s) {
        u32x4 fr;
        fr[0] = pk[kvb * 8 + 4 * s + 0];
        fr[1] = pk[kvb * 8 + 4 * s + 1];
        fr[2] = pk[kvb * 8 + 4 * s + 2];
        fr[3] = pk[kvb * 8 + 4 * s + 3];
        bf16x8 pfrag = __builtin_bit_cast(bf16x8, fr);
        #pragma unroll
        for (int db = 0; db < 2; ++db) {
          bf16x8 vf = *(const bf16x8*)&Vs[cur][swz(db * 32 + q31, kvb * 64 + s * 32 + h2 * 16)];
          acc_o[db] = __builtin_amdgcn_mfma_f32_32x32x16_bf16(vf, pfrag, acc_o[db], 0, 0, 0);
        }
      }
    __builtin_amdgcn_s_setprio(0);
  };

  // softmax from S-regs (fixed base 0), produce pk + update l
  auto softmax0 = [&](const f32x16& as0, const f32x16& as1, unsigned int* pk) {
    float ps = 0.f;
    #pragma unroll
    for (int kvb = 0; kvb < 2; ++kvb) {
      const f32x16& as = kvb ? as1 : as0;
      #pragma unroll
      for (int j = 0; j < 4; ++j) {
        float e0 = __builtin_amdgcn_exp2f(as[j * 4 + 0]);
        float e1 = __builtin_amdgcn_exp2f(as[j * 4 + 1]);
        float e2 = __builtin_amdgcn_exp2f(as[j * 4 + 2]);
        float e3 = __builtin_amdgcn_exp2f(as[j * 4 + 3]);
        ps += (e0 + e1) + (e2 + e3);
        pk[kvb * 8 + j * 2 + 0] = pack_bf16(e0, e1);
        pk[kvb * 8 + j * 2 + 1] = pack_bf16(e2, e3);
      }
    }
    l += ps;
  };

  if (!hasmask) {
    // ---- pipelined no-mask path ----
    f32x16 aA0 = {}, aA1 = {}, aB0 = {}, aB1 = {};
    stageK(0, kv0); stageV(0, kv0);           // queue: K0,V0
    stageK(1, kv0 + 64);                      // queue: K0,V0,K1 (6)
    VMCNT(4);                                 // K0 landed
    SB(); __builtin_amdgcn_s_barrier(); SB();
    qkt(0, aA0, aA1);                         // S(0)
    __builtin_amdgcn_s_barrier();             // all waves done reading Ks[0] as tile 0

    unsigned int pk[16];
    for (int it = 0; it < NT; it += 2) {
      // even sub-iter: consume A(S(it)), build B = S(it+1)
      {
        if (it + 1 < NT) stageV((it + 1) & 1, kv0 + (it + 1) * 64);
        if (it + 2 < NT) stageK(it & 1,       kv0 + (it + 2) * 64);
        if (it + 2 < NT)      { VMCNT(4); }   // pop {V(it), K(it+1)}
        else if (it + 1 < NT) { VMCNT(2); }
        else                  { VMCNT(0); }
        SB(); __builtin_amdgcn_s_barrier(); SB();
        if (it + 1 < NT) {
          aB0 = (f32x16){}; aB1 = (f32x16){};
          qkt((it + 1) & 1, aB0, aB1);        // MFMA, overlaps softmax below
        }
        softmax0(aA0, aA1, pk);               // VALU
        pv(it & 1, pk);
        __builtin_amdgcn_s_barrier();
      }
      // odd sub-iter: consume B(S(it+1)), build A = S(it+2)
      if (it + 1 < NT) {
        const int jt = it + 1;
        if (jt + 1 < NT) stageV((jt + 1) & 1, kv0 + (jt + 1) * 64);
        if (jt + 2 < NT) stageK(jt & 1,       kv0 + (jt + 2) * 64);
        if (jt + 2 < NT)      { VMCNT(4); }
        else if (jt + 1 < NT) { VMCNT(2); }
        else                  { VMCNT(0); }
        SB(); __builtin_amdgcn_s_barrier(); SB();
        if (jt + 1 < NT) {
          aA0 = (f32x16){}; aA1 = (f32x16){};
          qkt((jt + 1) & 1, aA0, aA1);
        }
        softmax0(aB0, aB1, pk);
        pv(jt & 1, pk);
        __builtin_amdgcn_s_barrier();
      }
    }
  } else {
    // ---- mask path (R15 structure, unchanged) ----
    auto stage = [&](int buf, int s0) {
      stageK(buf, s0);
      stageV(buf, s0);
    };
    float4 mk[8];
    auto tile_mask = [&](int cur) {
      f32x16 as0 = {}, as1 = {};
      qkt(cur, as0, as1);
      float sv[2][16];
      #pragma unroll
      for (int reg = 0; reg < 16; ++reg) {
        float m0v = (&mk[0 + (reg >> 2)].x)[reg & 3];
        float m1v = (&mk[4 + (reg >> 2)].x)[reg & 3];
        sv[0][reg] = fmaf(m0v, LOG2E, as0[reg]);
        sv[1][reg] = fmaf(m1v, LOG2E, as1[reg]);
      }
      float p0 = sv[0][0];
      #pragma unroll
      for (int i = 1; i < 16; ++i) p0 = fmaxf(p0, sv[0][i]);
      #pragma unroll
      for (int i = 0; i < 16; ++i) p0 = fmaxf(p0, sv[1][i]);
      float pmax = fmaxf(p0, __shfl_xor(p0, 32));
      if (__any(pmax > m + 8.f)) {
        float mnew = fmaxf(m, pmax);
        float sc = __builtin_amdgcn_exp2f(m - mnew);
        m = mnew;
        l *= sc;
        #pragma unroll
        for (int db = 0; db < 2; ++db)
          #pragma unroll
          for (int i = 0; i < 16; ++i) acc_o[db][i] *= sc;
      }
      float ps = 0.f;
      unsigned int pk[16];
      #pragma unroll
      for (int kvb = 0; kvb < 2; ++kvb)
        #pragma unroll
        for (int j = 0; j < 4; ++j) {
          float e0 = __builtin_amdgcn_exp2f(sv[kvb][j * 4 + 0] - m);
          float e1 = __builtin_amdgcn_exp2f(sv[kvb][j * 4 + 1] - m);
          float e2 = __builtin_amdgcn_exp2f(sv[kvb][j * 4 + 2] - m);
          float e3 = __builtin_amdgcn_exp2f(sv[kvb][j * 4 + 3] - m);
          ps += (e0 + e1) + (e2 + e3);
          pk[kvb * 8 + j * 2 + 0] = pack_bf16(e0, e1);
          pk[kvb * 8 + j * 2 + 1] = pack_bf16(e2, e3);
        }
      l += ps;
      pv(cur, pk);
    };

    stage(0, kv0);
    for (int it = 0; it < NT - 1; ++it) {
      const int s0 = kv0 + it * 64;
      #pragma unroll
      for (int kvb = 0; kvb < 2; ++kvb)
        #pragma unroll
        for (int g = 0; g < 4; ++g)
          mk[kvb * 4 + g] = *(const float4*)(mrow + s0 + kvb * 32 + g * 8 + 4 * h2);
      stage((it + 1) & 1, s0 + 64);
      VMCNT(12);
      SB();
      __builtin_amdgcn_s_barrier();
      SB();
      tile_mask(it & 1);
      __builtin_amdgcn_s_barrier();
    }
    const int s0 = kv0 + (NT - 1) * 64;
    #pragma unroll
    for (int kvb = 0; kvb < 2; ++kvb)
      #pragma unroll
      for (int g = 0; g < 4; ++g)
        mk[kvb * 4 + g] = *(const float4*)(mrow + s0 + kvb * 32 + g * 8 + 4 * h2);
    VMCNT(8);
    SB();
    __builtin_amdgcn_s_barrier();
    SB();
    tile_mask((NT - 1) & 1);
  }

  // epilogue: normalize by 1/l, store f16 partials
  float lf = l + __shfl_xor(l, 32);
  float lfinv = 1.f / lf;
  unsigned short* oprow = Op + (((size_t)z * T_TOK + qw) * NH + hh) * HD;
  #pragma unroll
  for (int db = 0; db < 2; ++db)
    #pragma unroll
    for (int g = 0; g < 4; ++g) {
      ushort4 o4;
      o4.x = f2h(acc_o[db][g * 4 + 0] * lfinv);
      o4.y = f2h(acc_o[db][g * 4 + 1] * lfinv);
      o4.z = f2h(acc_o[db][g * 4 + 2] * lfinv);
      o4.w = f2h(acc_o[db][g * 4 + 3] * lfinv);
      *(ushort4*)(oprow + db * 32 + g * 8 + 4 * h2) = o4;
    }
  if (h2 == 0) {
    size_t mi = ((size_t)z * T_TOK + qw) * NH + hh;
    Mp[mi] = m;
    Lp[mi] = lf;
  }
}

// ---------------- combine KV-split partials (normalized f16 Op) ----------------
__global__ __launch_bounds__(256) void combine(const unsigned short* __restrict__ Op,
                                               const float* __restrict__ Mp,
                                               const float* __restrict__ Lp,
                                               unsigned short* __restrict__ Ob) {
  int idx = blockIdx.x * 256 + threadIdx.x;
  int t = idx >> 8;
  int q4 = (idx & 255) * 4;
  int h = q4 >> 6, d = q4 & 63;
  float mz[KVSPLIT], lz[KVSPLIT];
  float ms = -INFINITY;
  #pragma unroll
  for (int zz = 0; zz < KVSPLIT; ++zz) {
    size_t mi = ((size_t)zz * T_TOK + t) * NH + h;
    mz[zz] = Mp[mi];
    lz[zz] = Lp[mi];
    ms = fmaxf(ms, mz[zz]);
  }
  float lsum = 0.f;
  float wl[KVSPLIT];
  #pragma unroll
  for (int zz = 0; zz < KVSPLIT; ++zz) {
    wl[zz] = lz[zz] * __builtin_amdgcn_exp2f(mz[zz] - ms);
    lsum += wl[zz];
  }
  float4 o = {0.f, 0.f, 0.f, 0.f};
  #pragma unroll
  for (int zz = 0; zz < KVSPLIT; ++zz) {
    ushort4 p = *(const ushort4*)(Op + (((size_t)zz * T_TOK + t) * NH + h) * HD + d);
    o.x += h2f(p.x) * wl[zz]; o.y += h2f(p.y) * wl[zz];
    o.z += h2f(p.z) * wl[zz]; o.w += h2f(p.w) * wl[zz];
  }
  float inv = 1.f / lsum;
  ushort4 ob;
  ob.x = f2bf(o.x * inv); ob.y = f2bf(o.y * inv);
  ob.z = f2bf(o.z * inv); ob.w = f2bf(o.w * inv);
  *(ushort4*)(Ob + (size_t)t * HID + q4) = ob;
}

extern "C" void kernel_launch(void* const* d_in, const int* in_sizes, int n_in,
                              void* d_out, int out_size, void* d_ws, size_t ws_size,
                              hipStream_t stream) {
  const float* X    = (const float*)d_in[0];
  const float* Wqkv = (const float*)d_in[1];
  const float* Wo   = (const float*)d_in[2];
  const float* mask = (const float*)d_in[3];
  const int*   pos  = (const int*)d_in[4];
  float* out = (float*)d_out;

  char* ws = (char*)d_ws;
  size_t off = 0;
  auto alloc = [&](size_t bytes) {
    char* p = ws + off;
    off += (bytes + 255) & ~(size_t)255;
    return p;
  };
  unsigned short* Xb    = (unsigned short*)alloc((size_t)T_TOK * HID * 2);
  unsigned short* WqkvT = (unsigned short*)alloc((size_t)3 * HID * HID * 2);
  unsigned short* WoT   = (unsigned short*)alloc((size_t)HID * HID * 2);
  unsigned short* Qh    = (unsigned short*)alloc((size_t)NH * T_TOK * HD * 2);
  unsigned short* Kh    = (unsigned short*)alloc((size_t)NH * T_TOK * HD * 2);
  unsigned short* Vt    = (unsigned short*)alloc((size_t)NH * HD * T_TOK * 2);
  unsigned short* Ob    = (unsigned short*)alloc((size_t)T_TOK * HID * 2);
  float*          ctab  = (float*)alloc((size_t)T_TOK * 32 * 4);
  float*          stab  = (float*)alloc((size_t)T_TOK * 32 * 4);
  float*          Mp    = (float*)alloc((size_t)KVSPLIT * T_TOK * NH * 4);
  float*          Lp    = (float*)alloc((size_t)KVSPLIT * T_TOK * NH * 4);
  int*            flags = (int*)alloc((size_t)KVSPLIT * NQB * 4);
  unsigned short* Op    = (unsigned short*)alloc((size_t)KVSPLIT * T_TOK * HID * 2);

  hipMemsetAsync(flags, 0, (size_t)KVSPLIT * NQB * 4, stream);

  prep<<<8320, 256, 0, stream>>>(X, Wqkv, Wo, pos, mask, Xb, WqkvT, WoT, ctab, stab, flags);

  gemm_qkv<<<dim3((3 * HID / 128) * (T_TOK / 128)), 256, 0, stream>>>(Xb, WqkvT, ctab, stab, Qh, Kh, Vt);

  flash_attn<<<dim3(NH * NQB * KVSPLIT), 256, 0, stream>>>(Qh, Kh, Vt, mask, flags, Op, Mp, Lp);
  combine<<<T_TOK, 256, 0, stream>>>(Op, Mp, Lp, Ob);

  gemm_bt<<<dim3((HID / 128) * (T_TOK / 128)), 256, 0, stream>>>(Ob, WoT, out, T_TOK, HID, HID);
}